// Round 1
// baseline (5808.427 us; speedup 1.0000x reference)
//
#include <hip/hip_runtime.h>
#include <math.h>

#define HID 256
#define INDIM 128

// ---------------- degree / norm ----------------
__global__ void k_init_deg(float* deg, int n) {
    int i = blockIdx.x * blockDim.x + threadIdx.x;
    if (i < n) deg[i] = 1.0f;  // self-loop
}

__global__ void k_count_deg(const int* __restrict__ dst, int E, float* deg) {
    int e = blockIdx.x * blockDim.x + threadIdx.x;
    if (e < E) atomicAdd(&deg[dst[e]], 1.0f);
}

__global__ void k_dinv(float* deg, int n) {
    int i = blockIdx.x * blockDim.x + threadIdx.x;
    if (i < n) deg[i] = rsqrtf(deg[i]);  // deg >= 1 always (self-loops)
}

// ---------------- dense GEMM: Y[n,HID] = X[n,K] @ W[K,HID] ----------------
template <int K>
__global__ __launch_bounds__(256) void k_gemm(const float* __restrict__ X,
                                              const float* __restrict__ W,
                                              float* __restrict__ Y, int n) {
    __shared__ float xs[16][K];
    int r0 = blockIdx.x * 16;
    for (int idx = threadIdx.x; idx < 16 * K; idx += 256) {
        int r = idx / K, k = idx % K;
        int row = r0 + r;
        xs[r][k] = (row < n) ? X[(size_t)row * K + k] : 0.0f;
    }
    __syncthreads();
    int c = threadIdx.x;  // output column, 0..255
    float acc[16];
#pragma unroll
    for (int r = 0; r < 16; r++) acc[r] = 0.0f;
    for (int k = 0; k < K; k++) {
        float w = W[k * HID + c];
#pragma unroll
        for (int r = 0; r < 16; r++) acc[r] += xs[r][k] * w;
    }
#pragma unroll
    for (int r = 0; r < 16; r++) {
        int row = r0 + r;
        if (row < n) Y[(size_t)row * HID + c] = acc[r];
    }
}

// ---------------- conv init: O[v] = b + H[v]*dinv[v]^2  (bias + self-loop msg)
__global__ __launch_bounds__(256) void k_conv_init(const float* __restrict__ H,
                                                   const float* __restrict__ dinv,
                                                   const float* __restrict__ b,
                                                   float* __restrict__ O, int n) {
    int v = blockIdx.x;
    int c = threadIdx.x;
    if (v >= n) return;
    float dv = dinv[v];
    float s = dv * dv;
    O[(size_t)v * HID + c] = b[c] + H[(size_t)v * HID + c] * s;
}

// ---------------- edge scatter: O[dst] += H[src]*dinv[src]*dinv[dst] --------
__global__ __launch_bounds__(256) void k_scatter(const float* __restrict__ H,
                                                 const float* __restrict__ dinv,
                                                 const int* __restrict__ src,
                                                 const int* __restrict__ dst,
                                                 int E, float* __restrict__ O) {
    int wave = (int)((blockIdx.x * blockDim.x + threadIdx.x) >> 6);
    int lane = threadIdx.x & 63;
    int nwaves = (int)((gridDim.x * blockDim.x) >> 6);
    for (int e = wave; e < E; e += nwaves) {
        int s = src[e], d = dst[e];
        float norm = dinv[s] * dinv[d];
        float4 v = ((const float4*)(H + (size_t)s * HID))[lane];
        float* op = O + (size_t)d * HID + lane * 4;
        atomicAdd(op + 0, v.x * norm);
        atomicAdd(op + 1, v.y * norm);
        atomicAdd(op + 2, v.z * norm);
        atomicAdd(op + 3, v.w * norm);
    }
}

// ---------------- relu in place ----------------
__global__ void k_relu(float* O, size_t total4) {
    size_t i = (size_t)blockIdx.x * blockDim.x + threadIdx.x;
    size_t stride = (size_t)gridDim.x * blockDim.x;
    float4* p = (float4*)O;
    for (; i < total4; i += stride) {
        float4 v = p[i];
        v.x = fmaxf(v.x, 0.f); v.y = fmaxf(v.y, 0.f);
        v.z = fmaxf(v.z, 0.f); v.w = fmaxf(v.w, 0.f);
        p[i] = v;
    }
}

// ---------------- mean pool per graph (batch sorted) ----------------
__global__ __launch_bounds__(256) void k_pool(const float* __restrict__ H,
                                              const int* __restrict__ batch,
                                              int n, float* __restrict__ G) {
    int g = blockIdx.x;
    int c = threadIdx.x;
    // lower_bound(batch, g)
    int lo = 0, hi = n;
    while (lo < hi) { int mid = (lo + hi) >> 1; if (batch[mid] < g) lo = mid + 1; else hi = mid; }
    int start = lo;
    lo = start; hi = n;
    while (lo < hi) { int mid = (lo + hi) >> 1; if (batch[mid] < g + 1) lo = mid + 1; else hi = mid; }
    int end = lo;
    float s = 0.0f;
    for (int v = start; v < end; v++) s += H[(size_t)v * HID + c];
    float cnt = (float)(end - start);
    G[g * HID + c] = s / fmaxf(cnt, 1.0f);
}

// ---------------- classifier: sigmoid(relu(G@W3+b3)@W4+b4) ----------------
__global__ __launch_bounds__(128) void k_cls(const float* __restrict__ G,
                                             const float* __restrict__ W3,
                                             const float* __restrict__ b3,
                                             const float* __restrict__ W4,
                                             const float* __restrict__ b4,
                                             float* __restrict__ out) {
    __shared__ float gr[256];
    __shared__ float red[2];
    int g = blockIdx.x, t = threadIdx.x;
    gr[t] = G[g * 256 + t];
    gr[t + 128] = G[g * 256 + t + 128];
    __syncthreads();
    float z = b3[t];
    for (int k = 0; k < 256; k++) z += gr[k] * W3[k * 128 + t];
    z = fmaxf(z, 0.0f);
    float p = z * W4[t];
    for (int off = 32; off; off >>= 1) p += __shfl_down(p, off);
    if ((t & 63) == 0) red[t >> 6] = p;
    __syncthreads();
    if (t == 0) {
        float tot = red[0] + red[1] + b4[0];
        out[g] = 1.0f / (1.0f + expf(-tot));
    }
}

// ---------------- launch ----------------
extern "C" void kernel_launch(void* const* d_in, const int* in_sizes, int n_in,
                              void* d_out, int out_size, void* d_ws, size_t ws_size,
                              hipStream_t stream) {
    const float* x  = (const float*)d_in[0];
    const int*   ei = (const int*)d_in[1];
    const int*   batch = (const int*)d_in[2];
    const float* W1 = (const float*)d_in[3];
    const float* b1 = (const float*)d_in[4];
    const float* W2 = (const float*)d_in[5];
    const float* b2 = (const float*)d_in[6];
    const float* W3 = (const float*)d_in[7];
    const float* b3 = (const float*)d_in[8];
    const float* W4 = (const float*)d_in[9];
    const float* b4 = (const float*)d_in[10];

    const int N = in_sizes[2];       // 50000 nodes
    const int E = in_sizes[1] / 2;   // 800000 edges
    const int G = out_size;          // 128 graphs

    char* w = (char*)d_ws;
    float* dinv = (float*)w;               w += ((size_t)N * 4 + 255) & ~(size_t)255;
    float* bufA = (float*)w;               w += (size_t)N * HID * 4;
    float* bufB = (float*)w;               w += (size_t)N * HID * 4;
    float* gbuf = (float*)w;               w += (size_t)G * HID * 4;

    const int* src = ei;
    const int* dst = ei + E;

    // degree + norm
    k_init_deg<<<(N + 255) / 256, 256, 0, stream>>>(dinv, N);
    k_count_deg<<<(E + 255) / 256, 256, 0, stream>>>(dst, E, dinv);
    k_dinv<<<(N + 255) / 256, 256, 0, stream>>>(dinv, N);

    int gemm_blocks = (N + 15) / 16;

    // ---- layer 1 ----
    k_gemm<INDIM><<<gemm_blocks, 256, 0, stream>>>(x, W1, bufA, N);
    k_conv_init<<<N, 256, 0, stream>>>(bufA, dinv, b1, bufB, N);
    k_scatter<<<4096, 256, 0, stream>>>(bufA, dinv, src, dst, E, bufB);
    k_relu<<<2048, 256, 0, stream>>>(bufB, (size_t)N * HID / 4);

    // ---- layer 2 ----
    k_gemm<HID><<<gemm_blocks, 256, 0, stream>>>(bufB, W2, bufA, N);
    k_conv_init<<<N, 256, 0, stream>>>(bufA, dinv, b2, bufB, N);
    k_scatter<<<4096, 256, 0, stream>>>(bufA, dinv, src, dst, E, bufB);
    k_relu<<<2048, 256, 0, stream>>>(bufB, (size_t)N * HID / 4);

    // ---- pool + classifier ----
    k_pool<<<G, 256, 0, stream>>>(bufB, batch, N, gbuf);
    k_cls<<<G, 128, 0, stream>>>(gbuf, W3, b3, W4, b4, (float*)d_out);
}

// Round 2
// 762.755 us; speedup vs baseline: 7.6151x; 7.6151x over previous
//
#include <hip/hip_runtime.h>
#include <math.h>

#define HID 256
#define INDIM 128

// ---------------- zero int buffer ----------------
__global__ void k_zero_int(int* p, int n) {
    int i = blockIdx.x * blockDim.x + threadIdx.x;
    if (i < n) p[i] = 0;
}

// ---------------- in-degree count (real edges only) ----------------
__global__ void k_count(const int* __restrict__ dst, int E, int* cnt) {
    int e = blockIdx.x * blockDim.x + threadIdx.x;
    if (e < E) atomicAdd(&cnt[dst[e]], 1);
}

// ---------------- dinv = rsqrt(deg+1)  (self-loop included) ----------------
__global__ void k_dinv(const int* __restrict__ cnt, float* dinv, int n) {
    int i = blockIdx.x * blockDim.x + threadIdx.x;
    if (i < n) dinv[i] = rsqrtf((float)(cnt[i] + 1));
}

// ---------------- 2-level exclusive scan of cnt -> row_start ----------------
__global__ __launch_bounds__(256) void k_scan_block(const int* __restrict__ cnt,
                                                    int* excl_tmp, int* blksum, int n) {
    __shared__ int sm[256];
    int t = threadIdx.x;
    int i = blockIdx.x * 256 + t;
    int c = (i < n) ? cnt[i] : 0;
    sm[t] = c;
    __syncthreads();
    for (int off = 1; off < 256; off <<= 1) {
        int v = (t >= off) ? sm[t - off] : 0;
        __syncthreads();
        sm[t] += v;
        __syncthreads();
    }
    if (i < n) excl_tmp[i] = sm[t] - c;
    if (t == 255) blksum[blockIdx.x] = sm[255];
}

__global__ __launch_bounds__(256) void k_scan_top(int* blksum, int nb) {
    __shared__ int sm[256];
    int t = threadIdx.x;
    int c = (t < nb) ? blksum[t] : 0;
    sm[t] = c;
    __syncthreads();
    for (int off = 1; off < 256; off <<= 1) {
        int v = (t >= off) ? sm[t - off] : 0;
        __syncthreads();
        sm[t] += v;
        __syncthreads();
    }
    if (t < nb) blksum[t] = sm[t] - c;  // exclusive
}

__global__ __launch_bounds__(256) void k_finalize_rows(const int* __restrict__ excl_tmp,
                                                       const int* __restrict__ blksum,
                                                       int* row_start, int* cursor,
                                                       int n, int E) {
    int i = blockIdx.x * 256 + threadIdx.x;
    if (i < n) {
        int r = excl_tmp[i] + blksum[blockIdx.x];
        row_start[i] = r;
        cursor[i] = r;
    }
    if (i == 0) row_start[n] = E;
}

// ---------------- fill CSR: csr_src grouped by dst ----------------
__global__ void k_fill(const int* __restrict__ src, const int* __restrict__ dst,
                       int E, int* cursor, int* csr_src) {
    int e = blockIdx.x * blockDim.x + threadIdx.x;
    if (e < E) {
        int p = atomicAdd(&cursor[dst[e]], 1);
        csr_src[p] = src[e];
    }
}

// ---------------- dense GEMM: Y[n,HID] = X[n,K] @ W[K,HID] ----------------
template <int K>
__global__ __launch_bounds__(256) void k_gemm(const float* __restrict__ X,
                                              const float* __restrict__ W,
                                              float* __restrict__ Y, int n) {
    __shared__ float xs[16][K];
    int r0 = blockIdx.x * 16;
    for (int idx = threadIdx.x; idx < 16 * K; idx += 256) {
        int r = idx / K, k = idx % K;
        int row = r0 + r;
        xs[r][k] = (row < n) ? X[(size_t)row * K + k] : 0.0f;
    }
    __syncthreads();
    int c = threadIdx.x;
    float acc[16];
#pragma unroll
    for (int r = 0; r < 16; r++) acc[r] = 0.0f;
    for (int k = 0; k < K; k++) {
        float w = W[k * HID + c];
#pragma unroll
        for (int r = 0; r < 16; r++) acc[r] += xs[r][k] * w;
    }
#pragma unroll
    for (int r = 0; r < 16; r++) {
        int row = r0 + r;
        if (row < n) Y[(size_t)row * HID + c] = acc[r];
    }
}

// ---- gather-aggregate: O[v] = relu(b + H[v]*dinv[v]^2 + sum_in H[s]*dinv[s]*dinv[v])
__global__ __launch_bounds__(256) void k_aggregate(const float* __restrict__ H,
                                                   const float* __restrict__ dinv,
                                                   const int* __restrict__ row_start,
                                                   const int* __restrict__ csr_src,
                                                   const float* __restrict__ bias,
                                                   float* __restrict__ O, int n) {
    int v = blockIdx.x;
    int c = threadIdx.x;
    if (v >= n) return;
    float dv = dinv[v];
    float acc = bias[c] + H[(size_t)v * HID + c] * dv * dv;
    int beg = row_start[v], end = row_start[v + 1];
    for (int i = beg; i < end; i++) {
        int s = csr_src[i];           // wave-uniform (broadcast)
        float w = dv * dinv[s];
        acc += H[(size_t)s * HID + c] * w;   // coalesced 1 KB row read
    }
    O[(size_t)v * HID + c] = fmaxf(acc, 0.0f);
}

// ---------------- mean pool per graph (batch sorted) ----------------
__global__ __launch_bounds__(256) void k_pool(const float* __restrict__ H,
                                              const int* __restrict__ batch,
                                              int n, float* __restrict__ G) {
    int g = blockIdx.x;
    int c = threadIdx.x;
    int lo = 0, hi = n;
    while (lo < hi) { int mid = (lo + hi) >> 1; if (batch[mid] < g) lo = mid + 1; else hi = mid; }
    int start = lo;
    lo = start; hi = n;
    while (lo < hi) { int mid = (lo + hi) >> 1; if (batch[mid] < g + 1) lo = mid + 1; else hi = mid; }
    int end = lo;
    float s = 0.0f;
    for (int v = start; v < end; v++) s += H[(size_t)v * HID + c];
    float cnt = (float)(end - start);
    G[g * HID + c] = s / fmaxf(cnt, 1.0f);
}

// ---------------- classifier: sigmoid(relu(G@W3+b3)@W4+b4) ----------------
__global__ __launch_bounds__(128) void k_cls(const float* __restrict__ G,
                                             const float* __restrict__ W3,
                                             const float* __restrict__ b3,
                                             const float* __restrict__ W4,
                                             const float* __restrict__ b4,
                                             float* __restrict__ out) {
    __shared__ float gr[256];
    __shared__ float red[2];
    int g = blockIdx.x, t = threadIdx.x;
    gr[t] = G[g * 256 + t];
    gr[t + 128] = G[g * 256 + t + 128];
    __syncthreads();
    float z = b3[t];
    for (int k = 0; k < 256; k++) z += gr[k] * W3[k * 128 + t];
    z = fmaxf(z, 0.0f);
    float p = z * W4[t];
    for (int off = 32; off; off >>= 1) p += __shfl_down(p, off);
    if ((t & 63) == 0) red[t >> 6] = p;
    __syncthreads();
    if (t == 0) {
        float tot = red[0] + red[1] + b4[0];
        out[g] = 1.0f / (1.0f + expf(-tot));
    }
}

// ---------------- launch ----------------
extern "C" void kernel_launch(void* const* d_in, const int* in_sizes, int n_in,
                              void* d_out, int out_size, void* d_ws, size_t ws_size,
                              hipStream_t stream) {
    const float* x  = (const float*)d_in[0];
    const int*   ei = (const int*)d_in[1];
    const int*   batch = (const int*)d_in[2];
    const float* W1 = (const float*)d_in[3];
    const float* b1 = (const float*)d_in[4];
    const float* W2 = (const float*)d_in[5];
    const float* b2 = (const float*)d_in[6];
    const float* W3 = (const float*)d_in[7];
    const float* b3 = (const float*)d_in[8];
    const float* W4 = (const float*)d_in[9];
    const float* b4 = (const float*)d_in[10];

    const int N = in_sizes[2];       // 50000 nodes
    const int E = in_sizes[1] / 2;   // 800000 edges
    const int G = out_size;          // 128 graphs
    const int NB = (N + 255) / 256;  // scan blocks (196)

    char* w = (char*)d_ws;
    float* dinv      = (float*)w;  w += ((size_t)N * 4 + 255) & ~(size_t)255;
    int*   cnt       = (int*)w;    w += ((size_t)N * 4 + 255) & ~(size_t)255;
    int*   excl_tmp  = (int*)w;    w += ((size_t)N * 4 + 255) & ~(size_t)255;
    int*   blksum    = (int*)w;    w += 256 * 4;
    int*   row_start = (int*)w;    w += ((size_t)(N + 1) * 4 + 255) & ~(size_t)255;
    int*   cursor    = (int*)w;    w += ((size_t)N * 4 + 255) & ~(size_t)255;
    int*   csr_src   = (int*)w;    w += ((size_t)E * 4 + 255) & ~(size_t)255;
    float* bufA      = (float*)w;  w += (size_t)N * HID * 4;
    float* bufB      = (float*)w;  w += (size_t)N * HID * 4;
    float* gbuf      = (float*)w;  w += (size_t)G * HID * 4;

    const int* src = ei;
    const int* dst = ei + E;

    // ---- CSR build (once) ----
    k_zero_int<<<NB, 256, 0, stream>>>(cnt, N);
    k_count<<<(E + 255) / 256, 256, 0, stream>>>(dst, E, cnt);
    k_dinv<<<NB, 256, 0, stream>>>(cnt, dinv, N);
    k_scan_block<<<NB, 256, 0, stream>>>(cnt, excl_tmp, blksum, N);
    k_scan_top<<<1, 256, 0, stream>>>(blksum, NB);
    k_finalize_rows<<<NB, 256, 0, stream>>>(excl_tmp, blksum, row_start, cursor, N, E);
    k_fill<<<(E + 255) / 256, 256, 0, stream>>>(src, dst, E, cursor, csr_src);

    int gemm_blocks = (N + 15) / 16;

    // ---- layer 1 ----
    k_gemm<INDIM><<<gemm_blocks, 256, 0, stream>>>(x, W1, bufA, N);
    k_aggregate<<<N, 256, 0, stream>>>(bufA, dinv, row_start, csr_src, b1, bufB, N);

    // ---- layer 2 ----
    k_gemm<HID><<<gemm_blocks, 256, 0, stream>>>(bufB, W2, bufA, N);
    k_aggregate<<<N, 256, 0, stream>>>(bufA, dinv, row_start, csr_src, b2, bufB, N);

    // ---- pool + classifier ----
    k_pool<<<G, 256, 0, stream>>>(bufB, batch, N, gbuf);
    k_cls<<<G, 128, 0, stream>>>(gbuf, W3, b3, W4, b4, (float*)d_out);
}

// Round 3
// 601.252 us; speedup vs baseline: 9.6605x; 1.2686x over previous
//
#include <hip/hip_runtime.h>
#include <math.h>

#define HID 256
#define INDIM 128

// ---------------- zero int buffer ----------------
__global__ void k_zero_int(int* p, int n) {
    int i = blockIdx.x * blockDim.x + threadIdx.x;
    if (i < n) p[i] = 0;
}

// ---------------- in-degree count (real edges only) ----------------
__global__ void k_count(const int* __restrict__ dst, int E, int* cnt) {
    int e = blockIdx.x * blockDim.x + threadIdx.x;
    if (e < E) atomicAdd(&cnt[dst[e]], 1);
}

// ---------------- dinv = rsqrt(deg+1)  (self-loop included) ----------------
__global__ void k_dinv(const int* __restrict__ cnt, float* dinv, int n) {
    int i = blockIdx.x * blockDim.x + threadIdx.x;
    if (i < n) dinv[i] = rsqrtf((float)(cnt[i] + 1));
}

// ---------------- 2-level exclusive scan of cnt -> row_start ----------------
__global__ __launch_bounds__(256) void k_scan_block(const int* __restrict__ cnt,
                                                    int* excl_tmp, int* blksum, int n) {
    __shared__ int sm[256];
    int t = threadIdx.x;
    int i = blockIdx.x * 256 + t;
    int c = (i < n) ? cnt[i] : 0;
    sm[t] = c;
    __syncthreads();
    for (int off = 1; off < 256; off <<= 1) {
        int v = (t >= off) ? sm[t - off] : 0;
        __syncthreads();
        sm[t] += v;
        __syncthreads();
    }
    if (i < n) excl_tmp[i] = sm[t] - c;
    if (t == 255) blksum[blockIdx.x] = sm[255];
}

__global__ __launch_bounds__(256) void k_scan_top(int* blksum, int nb) {
    __shared__ int sm[256];
    int t = threadIdx.x;
    int c = (t < nb) ? blksum[t] : 0;
    sm[t] = c;
    __syncthreads();
    for (int off = 1; off < 256; off <<= 1) {
        int v = (t >= off) ? sm[t - off] : 0;
        __syncthreads();
        sm[t] += v;
        __syncthreads();
    }
    if (t < nb) blksum[t] = sm[t] - c;  // exclusive
}

__global__ __launch_bounds__(256) void k_finalize_rows(const int* __restrict__ excl_tmp,
                                                       const int* __restrict__ blksum,
                                                       int* row_start, int* cursor,
                                                       int n, int E) {
    int i = blockIdx.x * 256 + threadIdx.x;
    if (i < n) {
        int r = excl_tmp[i] + blksum[blockIdx.x];
        row_start[i] = r;
        cursor[i] = r;
    }
    if (i == 0) row_start[n] = E;
}

// ---------------- fill CSR: csr_src grouped by dst ----------------
__global__ void k_fill(const int* __restrict__ src, const int* __restrict__ dst,
                       int E, int* cursor, int* csr_src) {
    int e = blockIdx.x * blockDim.x + threadIdx.x;
    if (e < E) {
        int p = atomicAdd(&cursor[dst[e]], 1);
        csr_src[p] = src[e];
    }
}

// ---- dense GEMM + dinv scale: Y[n,HID] = (X[n,K] @ W[K,HID]) * dinv[row] ----
template <int K>
__global__ __launch_bounds__(256) void k_gemm_scale(const float* __restrict__ X,
                                                    const float* __restrict__ W,
                                                    const float* __restrict__ dinv,
                                                    float* __restrict__ Y, int n) {
    __shared__ __align__(16) float xs[16][K];
    int r0 = blockIdx.x * 16;
    constexpr int NV = 16 * K / 4;  // float4 elements in tile
    const int t = threadIdx.x;
    for (int idx = t; idx < NV; idx += 256) {
        int r = idx / (K / 4);
        int q = idx % (K / 4);
        int row = r0 + r;
        float4 v = make_float4(0.f, 0.f, 0.f, 0.f);
        if (row < n) v = ((const float4*)(X + (size_t)row * K))[q];
        ((float4*)&xs[r][0])[q] = v;
    }
    __syncthreads();
    const int c = t;  // output column 0..255
    float acc[16];
#pragma unroll
    for (int r = 0; r < 16; r++) acc[r] = 0.f;
    for (int k = 0; k < K; k += 4) {
        float w0 = W[(k + 0) * HID + c];
        float w1 = W[(k + 1) * HID + c];
        float w2 = W[(k + 2) * HID + c];
        float w3 = W[(k + 3) * HID + c];
#pragma unroll
        for (int r = 0; r < 16; r++) {
            float4 xv = *(const float4*)&xs[r][k];
            acc[r] += xv.x * w0 + xv.y * w1 + xv.z * w2 + xv.w * w3;
        }
    }
#pragma unroll
    for (int r = 0; r < 16; r++) {
        int row = r0 + r;
        if (row < n) Y[(size_t)row * HID + c] = acc[r] * dinv[row];
    }
}

// ---- gather-aggregate (wave per node, float4 per lane):
//      out[v] = relu(b + dinv[v] * (H'[v] + sum_{s in N(v)} H'[s]))
//      where H' = (XW)*dinv  (self-loop term H'[v]*dv == h[v]*dv^2)
__global__ __launch_bounds__(256) void k_aggregate(const float* __restrict__ Hs,
                                                   const float* __restrict__ dinv,
                                                   const int* __restrict__ row_start,
                                                   const int* __restrict__ csr_src,
                                                   const float* __restrict__ bias,
                                                   float* __restrict__ O, int n) {
    int v = blockIdx.x * 4 + (threadIdx.x >> 6);
    int lane = threadIdx.x & 63;
    if (v >= n) return;
    const float4* H4 = (const float4*)Hs;
    float4 acc = H4[(size_t)v * 64 + lane];  // self term
    int beg = row_start[v], end = row_start[v + 1];
    int i = beg;
    for (; i + 4 <= end; i += 4) {
        int s0 = csr_src[i + 0];
        int s1 = csr_src[i + 1];
        int s2 = csr_src[i + 2];
        int s3 = csr_src[i + 3];
        float4 a = H4[(size_t)s0 * 64 + lane];
        float4 b = H4[(size_t)s1 * 64 + lane];
        float4 c = H4[(size_t)s2 * 64 + lane];
        float4 d = H4[(size_t)s3 * 64 + lane];
        acc.x += (a.x + b.x) + (c.x + d.x);
        acc.y += (a.y + b.y) + (c.y + d.y);
        acc.z += (a.z + b.z) + (c.z + d.z);
        acc.w += (a.w + b.w) + (c.w + d.w);
    }
    for (; i < end; i++) {
        int s = csr_src[i];
        float4 a = H4[(size_t)s * 64 + lane];
        acc.x += a.x; acc.y += a.y; acc.z += a.z; acc.w += a.w;
    }
    float dv = dinv[v];
    float4 bb = ((const float4*)bias)[lane];
    float4 o;
    o.x = fmaxf(fmaf(dv, acc.x, bb.x), 0.f);
    o.y = fmaxf(fmaf(dv, acc.y, bb.y), 0.f);
    o.z = fmaxf(fmaf(dv, acc.z, bb.z), 0.f);
    o.w = fmaxf(fmaf(dv, acc.w, bb.w), 0.f);
    ((float4*)O)[(size_t)v * 64 + lane] = o;
}

// ---------------- mean pool per graph (batch sorted), 4 waves ----------------
__global__ __launch_bounds__(256) void k_pool(const float* __restrict__ H,
                                              const int* __restrict__ batch,
                                              int n, float* __restrict__ G) {
    int g = blockIdx.x;
    int w = threadIdx.x >> 6;
    int lane = threadIdx.x & 63;
    int lo = 0, hi = n;
    while (lo < hi) { int m = (lo + hi) >> 1; if (batch[m] < g) lo = m + 1; else hi = m; }
    int start = lo;
    hi = n;
    while (lo < hi) { int m = (lo + hi) >> 1; if (batch[m] <= g) lo = m + 1; else hi = m; }
    int end = lo;
    const float4* H4 = (const float4*)H;
    float4 acc = make_float4(0.f, 0.f, 0.f, 0.f);
    for (int v = start + w; v < end; v += 4) {
        float4 a = H4[(size_t)v * 64 + lane];
        acc.x += a.x; acc.y += a.y; acc.z += a.z; acc.w += a.w;
    }
    __shared__ float4 red[4][64];
    red[w][lane] = acc;
    __syncthreads();
    if (w == 0) {
        float4 r0 = red[0][lane], r1 = red[1][lane], r2 = red[2][lane], r3 = red[3][lane];
        float inv = 1.0f / fmaxf((float)(end - start), 1.0f);
        float4 o;
        o.x = (r0.x + r1.x + r2.x + r3.x) * inv;
        o.y = (r0.y + r1.y + r2.y + r3.y) * inv;
        o.z = (r0.z + r1.z + r2.z + r3.z) * inv;
        o.w = (r0.w + r1.w + r2.w + r3.w) * inv;
        ((float4*)G)[g * 64 + lane] = o;
    }
}

// ---------------- classifier: sigmoid(relu(G@W3+b3)@W4+b4) ----------------
__global__ __launch_bounds__(128) void k_cls(const float* __restrict__ G,
                                             const float* __restrict__ W3,
                                             const float* __restrict__ b3,
                                             const float* __restrict__ W4,
                                             const float* __restrict__ b4,
                                             float* __restrict__ out) {
    __shared__ float gr[256];
    __shared__ float red[2];
    int g = blockIdx.x, t = threadIdx.x;
    gr[t] = G[g * 256 + t];
    gr[t + 128] = G[g * 256 + t + 128];
    __syncthreads();
    float z = b3[t];
    for (int k = 0; k < 256; k++) z += gr[k] * W3[k * 128 + t];
    z = fmaxf(z, 0.0f);
    float p = z * W4[t];
    for (int off = 32; off; off >>= 1) p += __shfl_down(p, off);
    if ((t & 63) == 0) red[t >> 6] = p;
    __syncthreads();
    if (t == 0) {
        float tot = red[0] + red[1] + b4[0];
        out[g] = 1.0f / (1.0f + expf(-tot));
    }
}

// ---------------- launch ----------------
extern "C" void kernel_launch(void* const* d_in, const int* in_sizes, int n_in,
                              void* d_out, int out_size, void* d_ws, size_t ws_size,
                              hipStream_t stream) {
    const float* x  = (const float*)d_in[0];
    const int*   ei = (const int*)d_in[1];
    const int*   batch = (const int*)d_in[2];
    const float* W1 = (const float*)d_in[3];
    const float* b1 = (const float*)d_in[4];
    const float* W2 = (const float*)d_in[5];
    const float* b2 = (const float*)d_in[6];
    const float* W3 = (const float*)d_in[7];
    const float* b3 = (const float*)d_in[8];
    const float* W4 = (const float*)d_in[9];
    const float* b4 = (const float*)d_in[10];

    const int N = in_sizes[2];       // 50000 nodes
    const int E = in_sizes[1] / 2;   // 800000 edges
    const int G = out_size;          // 128 graphs
    const int NB = (N + 255) / 256;  // scan blocks

    char* w = (char*)d_ws;
    float* dinv      = (float*)w;  w += ((size_t)N * 4 + 255) & ~(size_t)255;
    int*   cnt       = (int*)w;    w += ((size_t)N * 4 + 255) & ~(size_t)255;
    int*   excl_tmp  = (int*)w;    w += ((size_t)N * 4 + 255) & ~(size_t)255;
    int*   blksum    = (int*)w;    w += 256 * 4;
    int*   row_start = (int*)w;    w += ((size_t)(N + 1) * 4 + 255) & ~(size_t)255;
    int*   cursor    = (int*)w;    w += ((size_t)N * 4 + 255) & ~(size_t)255;
    int*   csr_src   = (int*)w;    w += ((size_t)E * 4 + 255) & ~(size_t)255;
    float* bufA      = (float*)w;  w += (size_t)N * HID * 4;  // H' (scaled gemm out)
    float* bufB      = (float*)w;  w += (size_t)N * HID * 4;  // h (post aggregate)
    float* gbuf      = (float*)w;  w += (size_t)G * HID * 4;

    const int* src = ei;
    const int* dst = ei + E;

    // ---- CSR build (once) ----
    k_zero_int<<<NB, 256, 0, stream>>>(cnt, N);
    k_count<<<(E + 255) / 256, 256, 0, stream>>>(dst, E, cnt);
    k_dinv<<<NB, 256, 0, stream>>>(cnt, dinv, N);
    k_scan_block<<<NB, 256, 0, stream>>>(cnt, excl_tmp, blksum, N);
    k_scan_top<<<1, 256, 0, stream>>>(blksum, NB);
    k_finalize_rows<<<NB, 256, 0, stream>>>(excl_tmp, blksum, row_start, cursor, N, E);
    k_fill<<<(E + 255) / 256, 256, 0, stream>>>(src, dst, E, cursor, csr_src);

    const int gemm_blocks = (N + 15) / 16;
    const int agg_blocks  = (N + 3) / 4;

    // ---- layer 1 ----
    k_gemm_scale<INDIM><<<gemm_blocks, 256, 0, stream>>>(x, W1, dinv, bufA, N);
    k_aggregate<<<agg_blocks, 256, 0, stream>>>(bufA, dinv, row_start, csr_src, b1, bufB, N);

    // ---- layer 2 ----
    k_gemm_scale<HID><<<gemm_blocks, 256, 0, stream>>>(bufB, W2, dinv, bufA, N);
    k_aggregate<<<agg_blocks, 256, 0, stream>>>(bufA, dinv, row_start, csr_src, b2, bufB, N);

    // ---- pool + classifier ----
    k_pool<<<G, 256, 0, stream>>>(bufB, batch, N, gbuf);
    k_cls<<<G, 128, 0, stream>>>(gbuf, W3, b3, W4, b4, (float*)d_out);
}

// Round 4
// 378.245 us; speedup vs baseline: 15.3563x; 1.5896x over previous
//
#include <hip/hip_runtime.h>
#include <math.h>

#define HID 256
#define INDIM 128

typedef short s16x8 __attribute__((ext_vector_type(8)));
typedef float f32x4 __attribute__((ext_vector_type(4)));

// ---- bf16 helpers (RNE, finite inputs) ----
static __device__ __forceinline__ unsigned short f2bf(float f) {
    unsigned int u = __float_as_uint(f);
    unsigned int r = (u + 0x7fffu + ((u >> 16) & 1u)) >> 16;
    return (unsigned short)r;
}
#define BFLO(x) __uint_as_float((x) << 16)
#define BFHI(x) __uint_as_float((x) & 0xffff0000u)

// ---------------- zero int buffer ----------------
__global__ void k_zero_int(int* p, int n) {
    int i = blockIdx.x * blockDim.x + threadIdx.x;
    if (i < n) p[i] = 0;
}

// ---------------- in-degree count ----------------
__global__ void k_count(const int* __restrict__ dst, int E, int* cnt) {
    int e = blockIdx.x * blockDim.x + threadIdx.x;
    if (e < E) atomicAdd(&cnt[dst[e]], 1);
}

// ---------------- dinv = rsqrt(deg+1) ----------------
__global__ void k_dinv(const int* __restrict__ cnt, float* dinv, int n) {
    int i = blockIdx.x * blockDim.x + threadIdx.x;
    if (i < n) dinv[i] = rsqrtf((float)(cnt[i] + 1));
}

// ---------------- 2-level exclusive scan ----------------
__global__ __launch_bounds__(256) void k_scan_block(const int* __restrict__ cnt,
                                                    int* excl_tmp, int* blksum, int n) {
    __shared__ int sm[256];
    int t = threadIdx.x;
    int i = blockIdx.x * 256 + t;
    int c = (i < n) ? cnt[i] : 0;
    sm[t] = c;
    __syncthreads();
    for (int off = 1; off < 256; off <<= 1) {
        int v = (t >= off) ? sm[t - off] : 0;
        __syncthreads();
        sm[t] += v;
        __syncthreads();
    }
    if (i < n) excl_tmp[i] = sm[t] - c;
    if (t == 255) blksum[blockIdx.x] = sm[255];
}

__global__ __launch_bounds__(256) void k_scan_top(int* blksum, int nb) {
    __shared__ int sm[256];
    int t = threadIdx.x;
    int c = (t < nb) ? blksum[t] : 0;
    sm[t] = c;
    __syncthreads();
    for (int off = 1; off < 256; off <<= 1) {
        int v = (t >= off) ? sm[t - off] : 0;
        __syncthreads();
        sm[t] += v;
        __syncthreads();
    }
    if (t < nb) blksum[t] = sm[t] - c;
}

__global__ __launch_bounds__(256) void k_finalize_rows(const int* __restrict__ excl_tmp,
                                                       const int* __restrict__ blksum,
                                                       int* row_start, int* cursor,
                                                       int n, int E) {
    int i = blockIdx.x * 256 + threadIdx.x;
    if (i < n) {
        int r = excl_tmp[i] + blksum[blockIdx.x];
        row_start[i] = r;
        cursor[i] = r;
    }
    if (i == 0) row_start[n] = E;
}

// ---------------- fill CSR ----------------
__global__ void k_fill(const int* __restrict__ src, const int* __restrict__ dst,
                       int E, int* cursor, int* csr_src) {
    int e = blockIdx.x * blockDim.x + threadIdx.x;
    if (e < E) {
        int p = atomicAdd(&cursor[dst[e]], 1);
        csr_src[p] = src[e];
    }
}

// ---------------- casts ----------------
__global__ void k_cast_bf16(const float* __restrict__ in, unsigned short* __restrict__ out, int n4) {
    int i = blockIdx.x * blockDim.x + threadIdx.x;
    if (i < n4) {
        float4 v = ((const float4*)in)[i];
        ushort4 o;
        o.x = f2bf(v.x); o.y = f2bf(v.y); o.z = f2bf(v.z); o.w = f2bf(v.w);
        ((ushort4*)out)[i] = o;
    }
}

// Wt[c][k] = bf16(W[k][c]); launch <<<256, K>>>
template <int K>
__global__ void k_wt(const float* __restrict__ W, unsigned short* __restrict__ Wt) {
    int c = blockIdx.x;
    int t = threadIdx.x;
    Wt[(size_t)c * K + t] = f2bf(W[(size_t)t * HID + c]);
}

// ---- MFMA GEMM + dinv scale: Yb[n,HID](bf16) = (Xb[n,K](bf16) @ W) * dinv[row]
// block: 16 rows x 256 cols, 4 waves x (4 col-tiles of 16)
template <int K>
__global__ __launch_bounds__(256) void k_gemm_mfma(const unsigned short* __restrict__ Xb,
                                                   const unsigned short* __restrict__ Wt,
                                                   const float* __restrict__ dinv,
                                                   unsigned short* __restrict__ Yb, int n) {
    int r0 = blockIdx.x * 16;
    int w = threadIdx.x >> 6;
    int lane = threadIdx.x & 63;
    int ar = lane & 15;          // A row within tile / B col within tile
    int ak = (lane >> 4) * 8;    // k sub-block
    int arow = r0 + ar;
    if (arow >= n) arow = n - 1;  // clamp (store guarded)
    f32x4 acc[4] = {f32x4{0,0,0,0}, f32x4{0,0,0,0}, f32x4{0,0,0,0}, f32x4{0,0,0,0}};
#pragma unroll
    for (int kk = 0; kk < K; kk += 32) {
        s16x8 a = *(const s16x8*)(Xb + (size_t)arow * K + kk + ak);
#pragma unroll
        for (int ct = 0; ct < 4; ct++) {
            int c = w * 64 + ct * 16 + ar;
            s16x8 b = *(const s16x8*)(Wt + (size_t)c * K + kk + ak);
            acc[ct] = __builtin_amdgcn_mfma_f32_16x16x32_bf16(a, b, acc[ct], 0, 0, 0);
        }
    }
    float dv[4];
    int rbase = r0 + (lane >> 4) * 4;
#pragma unroll
    for (int j = 0; j < 4; j++) dv[j] = (rbase + j < n) ? dinv[rbase + j] : 0.0f;
#pragma unroll
    for (int ct = 0; ct < 4; ct++) {
        int c = w * 64 + ct * 16 + ar;
#pragma unroll
        for (int j = 0; j < 4; j++) {
            int r = rbase + j;
            if (r < n) Yb[(size_t)r * HID + c] = f2bf(acc[ct][j] * dv[j]);
        }
    }
}

// ---- gather-aggregate bf16 (wave per node, 8B/lane):
//      out[v] = relu(b + dinv[v] * (H'[v] + sum_in H'[s]))  , H' = (XW)*dinv
__global__ __launch_bounds__(256) void k_aggregate_bf(const unsigned short* __restrict__ Hb,
                                                      const float* __restrict__ dinv,
                                                      const int* __restrict__ row_start,
                                                      const int* __restrict__ csr_src,
                                                      const float* __restrict__ bias,
                                                      unsigned short* __restrict__ O, int n) {
    int v = blockIdx.x * 4 + (threadIdx.x >> 6);
    int lane = threadIdx.x & 63;
    if (v >= n) return;
    const uint2* H2 = (const uint2*)Hb;
    uint2 u = H2[(size_t)v * 64 + lane];  // self term
    float a0 = BFLO(u.x), a1 = BFHI(u.x), a2 = BFLO(u.y), a3 = BFHI(u.y);
    int beg = row_start[v], end = row_start[v + 1];
    int i = beg;
    for (; i + 4 <= end; i += 4) {
        int s0 = csr_src[i + 0];
        int s1 = csr_src[i + 1];
        int s2 = csr_src[i + 2];
        int s3 = csr_src[i + 3];
        uint2 e0 = H2[(size_t)s0 * 64 + lane];
        uint2 e1 = H2[(size_t)s1 * 64 + lane];
        uint2 e2 = H2[(size_t)s2 * 64 + lane];
        uint2 e3 = H2[(size_t)s3 * 64 + lane];
        a0 += (BFLO(e0.x) + BFLO(e1.x)) + (BFLO(e2.x) + BFLO(e3.x));
        a1 += (BFHI(e0.x) + BFHI(e1.x)) + (BFHI(e2.x) + BFHI(e3.x));
        a2 += (BFLO(e0.y) + BFLO(e1.y)) + (BFLO(e2.y) + BFLO(e3.y));
        a3 += (BFHI(e0.y) + BFHI(e1.y)) + (BFHI(e2.y) + BFHI(e3.y));
    }
    for (; i < end; i++) {
        int s = csr_src[i];
        uint2 e0 = H2[(size_t)s * 64 + lane];
        a0 += BFLO(e0.x); a1 += BFHI(e0.x); a2 += BFLO(e0.y); a3 += BFHI(e0.y);
    }
    float dvv = dinv[v];
    float4 bb = ((const float4*)bias)[lane];
    float o0 = fmaxf(fmaf(dvv, a0, bb.x), 0.f);
    float o1 = fmaxf(fmaf(dvv, a1, bb.y), 0.f);
    float o2 = fmaxf(fmaf(dvv, a2, bb.z), 0.f);
    float o3 = fmaxf(fmaf(dvv, a3, bb.w), 0.f);
    uint2 outw;
    outw.x = (unsigned int)f2bf(o0) | ((unsigned int)f2bf(o1) << 16);
    outw.y = (unsigned int)f2bf(o2) | ((unsigned int)f2bf(o3) << 16);
    ((uint2*)O)[(size_t)v * 64 + lane] = outw;
}

// ---------------- mean pool per graph (bf16 in, fp32 out), 4 waves ----------------
__global__ __launch_bounds__(256) void k_pool(const unsigned short* __restrict__ Hb,
                                              const int* __restrict__ batch,
                                              int n, float* __restrict__ G) {
    int g = blockIdx.x;
    int w = threadIdx.x >> 6;
    int lane = threadIdx.x & 63;
    int lo = 0, hi = n;
    while (lo < hi) { int m = (lo + hi) >> 1; if (batch[m] < g) lo = m + 1; else hi = m; }
    int start = lo;
    hi = n;
    while (lo < hi) { int m = (lo + hi) >> 1; if (batch[m] <= g) lo = m + 1; else hi = m; }
    int end = lo;
    const uint2* H2 = (const uint2*)Hb;
    float a0 = 0.f, a1 = 0.f, a2 = 0.f, a3 = 0.f;
    for (int v = start + w; v < end; v += 4) {
        uint2 u = H2[(size_t)v * 64 + lane];
        a0 += BFLO(u.x); a1 += BFHI(u.x); a2 += BFLO(u.y); a3 += BFHI(u.y);
    }
    __shared__ float4 red[4][64];
    red[w][lane] = make_float4(a0, a1, a2, a3);
    __syncthreads();
    if (w == 0) {
        float4 r0 = red[0][lane], r1 = red[1][lane], r2 = red[2][lane], r3 = red[3][lane];
        float inv = 1.0f / fmaxf((float)(end - start), 1.0f);
        float4 o;
        o.x = (r0.x + r1.x + r2.x + r3.x) * inv;
        o.y = (r0.y + r1.y + r2.y + r3.y) * inv;
        o.z = (r0.z + r1.z + r2.z + r3.z) * inv;
        o.w = (r0.w + r1.w + r2.w + r3.w) * inv;
        ((float4*)G)[g * 64 + lane] = o;
    }
}

// ---------------- classifier: sigmoid(relu(G@W3+b3)@W4+b4) ----------------
__global__ __launch_bounds__(128) void k_cls(const float* __restrict__ G,
                                             const float* __restrict__ W3,
                                             const float* __restrict__ b3,
                                             const float* __restrict__ W4,
                                             const float* __restrict__ b4,
                                             float* __restrict__ out) {
    __shared__ float gr[256];
    __shared__ float red[2];
    int g = blockIdx.x, t = threadIdx.x;
    gr[t] = G[g * 256 + t];
    gr[t + 128] = G[g * 256 + t + 128];
    __syncthreads();
    float z = b3[t];
    for (int k = 0; k < 256; k++) z += gr[k] * W3[k * 128 + t];
    z = fmaxf(z, 0.0f);
    float p = z * W4[t];
    for (int off = 32; off; off >>= 1) p += __shfl_down(p, off);
    if ((t & 63) == 0) red[t >> 6] = p;
    __syncthreads();
    if (t == 0) {
        float tot = red[0] + red[1] + b4[0];
        out[g] = 1.0f / (1.0f + expf(-tot));
    }
}

// ---------------- launch ----------------
extern "C" void kernel_launch(void* const* d_in, const int* in_sizes, int n_in,
                              void* d_out, int out_size, void* d_ws, size_t ws_size,
                              hipStream_t stream) {
    const float* x  = (const float*)d_in[0];
    const int*   ei = (const int*)d_in[1];
    const int*   batch = (const int*)d_in[2];
    const float* W1 = (const float*)d_in[3];
    const float* b1 = (const float*)d_in[4];
    const float* W2 = (const float*)d_in[5];
    const float* b2 = (const float*)d_in[6];
    const float* W3 = (const float*)d_in[7];
    const float* b3 = (const float*)d_in[8];
    const float* W4 = (const float*)d_in[9];
    const float* b4 = (const float*)d_in[10];

    const int N = in_sizes[2];       // 50000 nodes
    const int E = in_sizes[1] / 2;   // 800000 edges
    const int G = out_size;          // 128 graphs
    const int NB = (N + 255) / 256;

    char* w = (char*)d_ws;
    float* dinv      = (float*)w;  w += ((size_t)N * 4 + 255) & ~(size_t)255;
    int*   cnt       = (int*)w;    w += ((size_t)N * 4 + 255) & ~(size_t)255;
    int*   excl_tmp  = (int*)w;    w += ((size_t)N * 4 + 255) & ~(size_t)255;
    int*   blksum    = (int*)w;    w += 256 * 4;
    int*   row_start = (int*)w;    w += ((size_t)(N + 1) * 4 + 255) & ~(size_t)255;
    int*   cursor    = (int*)w;    w += ((size_t)N * 4 + 255) & ~(size_t)255;
    int*   csr_src   = (int*)w;    w += ((size_t)E * 4 + 255) & ~(size_t)255;
    unsigned short* xb   = (unsigned short*)w;  w += ((size_t)N * INDIM * 2 + 255) & ~(size_t)255;
    unsigned short* w1t  = (unsigned short*)w;  w += ((size_t)INDIM * HID * 2 + 255) & ~(size_t)255;
    unsigned short* w2t  = (unsigned short*)w;  w += ((size_t)HID * HID * 2 + 255) & ~(size_t)255;
    unsigned short* bufA = (unsigned short*)w;  w += (size_t)N * HID * 2;  // H' (scaled gemm out)
    unsigned short* bufB = (unsigned short*)w;  w += (size_t)N * HID * 2;  // h (post aggregate)
    float* gbuf      = (float*)w;  w += (size_t)G * HID * 4;

    const int* src = ei;
    const int* dst = ei + E;

    // ---- casts / weight transpose ----
    int n4 = N * INDIM / 4;
    k_cast_bf16<<<(n4 + 255) / 256, 256, 0, stream>>>(x, xb, n4);
    k_wt<INDIM><<<HID, INDIM, 0, stream>>>(W1, w1t);
    k_wt<HID><<<HID, HID, 0, stream>>>(W2, w2t);

    // ---- CSR build ----
    k_zero_int<<<NB, 256, 0, stream>>>(cnt, N);
    k_count<<<(E + 255) / 256, 256, 0, stream>>>(dst, E, cnt);
    k_dinv<<<NB, 256, 0, stream>>>(cnt, dinv, N);
    k_scan_block<<<NB, 256, 0, stream>>>(cnt, excl_tmp, blksum, N);
    k_scan_top<<<1, 256, 0, stream>>>(blksum, NB);
    k_finalize_rows<<<NB, 256, 0, stream>>>(excl_tmp, blksum, row_start, cursor, N, E);
    k_fill<<<(E + 255) / 256, 256, 0, stream>>>(src, dst, E, cursor, csr_src);

    const int gemm_blocks = (N + 15) / 16;
    const int agg_blocks  = (N + 3) / 4;

    // ---- layer 1 ----
    k_gemm_mfma<INDIM><<<gemm_blocks, 256, 0, stream>>>(xb, w1t, dinv, bufA, N);
    k_aggregate_bf<<<agg_blocks, 256, 0, stream>>>(bufA, dinv, row_start, csr_src, b1, bufB, N);

    // ---- layer 2 ----
    k_gemm_mfma<HID><<<gemm_blocks, 256, 0, stream>>>(bufB, w2t, dinv, bufA, N);
    k_aggregate_bf<<<agg_blocks, 256, 0, stream>>>(bufA, dinv, row_start, csr_src, b2, bufB, N);

    // ---- pool + classifier ----
    k_pool<<<G, 256, 0, stream>>>(bufB, batch, N, gbuf);
    k_cls<<<G, 128, 0, stream>>>(gbuf, W3, b3, W4, b4, (float*)d_out);
}

// Round 5
// 353.534 us; speedup vs baseline: 16.4296x; 1.0699x over previous
//
#include <hip/hip_runtime.h>
#include <math.h>

#define HID 256
#define INDIM 128

typedef short s16x8 __attribute__((ext_vector_type(8)));
typedef float f32x4 __attribute__((ext_vector_type(4)));

// ---- bf16 helpers (RNE, finite inputs) ----
static __device__ __forceinline__ unsigned short f2bf(float f) {
    unsigned int u = __float_as_uint(f);
    unsigned int r = (u + 0x7fffu + ((u >> 16) & 1u)) >> 16;
    return (unsigned short)r;
}
#define BFLO(x) __uint_as_float((x) << 16)
#define BFHI(x) __uint_as_float((x) & 0xffff0000u)

// ---------------- in-degree count ----------------
__global__ void k_count(const int* __restrict__ dst, int E, int* cnt) {
    int e = blockIdx.x * blockDim.x + threadIdx.x;
    if (e < E) atomicAdd(&cnt[dst[e]], 1);
}

// ---------------- 2-level exclusive scan ----------------
__global__ __launch_bounds__(256) void k_scan_block(const int* __restrict__ cnt,
                                                    int* excl_tmp, int* blksum, int n) {
    __shared__ int sm[256];
    int t = threadIdx.x;
    int i = blockIdx.x * 256 + t;
    int c = (i < n) ? cnt[i] : 0;
    sm[t] = c;
    __syncthreads();
    for (int off = 1; off < 256; off <<= 1) {
        int v = (t >= off) ? sm[t - off] : 0;
        __syncthreads();
        sm[t] += v;
        __syncthreads();
    }
    if (i < n) excl_tmp[i] = sm[t] - c;
    if (t == 255) blksum[blockIdx.x] = sm[255];
}

__global__ __launch_bounds__(256) void k_scan_top(int* blksum, int nb) {
    __shared__ int sm[256];
    int t = threadIdx.x;
    int c = (t < nb) ? blksum[t] : 0;
    sm[t] = c;
    __syncthreads();
    for (int off = 1; off < 256; off <<= 1) {
        int v = (t >= off) ? sm[t - off] : 0;
        __syncthreads();
        sm[t] += v;
        __syncthreads();
    }
    if (t < nb) blksum[t] = sm[t] - c;
}

// rows + cursor + dinv in one pass
__global__ __launch_bounds__(256) void k_finalize_rows(const int* __restrict__ excl_tmp,
                                                       const int* __restrict__ blksum,
                                                       const int* __restrict__ cnt,
                                                       int* row_start, int* cursor,
                                                       float* dinv, int n, int E) {
    int i = blockIdx.x * 256 + threadIdx.x;
    if (i < n) {
        int r = excl_tmp[i] + blksum[blockIdx.x];
        row_start[i] = r;
        cursor[i] = r;
        dinv[i] = rsqrtf((float)(cnt[i] + 1));
    }
    if (i == 0) row_start[n] = E;
}

// ---------------- fill CSR ----------------
__global__ void k_fill(const int* __restrict__ src, const int* __restrict__ dst,
                       int E, int* cursor, int* csr_src) {
    int e = blockIdx.x * blockDim.x + threadIdx.x;
    if (e < E) {
        int p = atomicAdd(&cursor[dst[e]], 1);
        csr_src[p] = src[e];
    }
}

// ---------------- casts ----------------
__global__ void k_cast_bf16(const float* __restrict__ in, unsigned short* __restrict__ out, int n4) {
    int i = blockIdx.x * blockDim.x + threadIdx.x;
    if (i < n4) {
        float4 v = ((const float4*)in)[i];
        ushort4 o;
        o.x = f2bf(v.x); o.y = f2bf(v.y); o.z = f2bf(v.z); o.w = f2bf(v.w);
        ((ushort4*)out)[i] = o;
    }
}

// Wt[c][k] = bf16(W[k][c]); launch <<<256, K>>>
template <int K>
__global__ void k_wt(const float* __restrict__ W, unsigned short* __restrict__ Wt) {
    int c = blockIdx.x;
    int t = threadIdx.x;
    Wt[(size_t)c * K + t] = f2bf(W[(size_t)t * HID + c]);
}

// ---- MFMA GEMM + dinv scale: Yb[n,HID](bf16) = (Xb[n,K](bf16) @ W) * dinv[row]
// block: 64 rows x 256 cols; wave: 64 rows x 64 cols = 4 row-tiles x 4 col-tiles
template <int K>
__global__ __launch_bounds__(256) void k_gemm_mfma(const unsigned short* __restrict__ Xb,
                                                   const unsigned short* __restrict__ Wt,
                                                   const float* __restrict__ dinv,
                                                   unsigned short* __restrict__ Yb, int n) {
    const int r0 = blockIdx.x * 64;
    const int w = threadIdx.x >> 6;
    const int lane = threadIdx.x & 63;
    const int ar = lane & 15;          // A row within tile / B col within tile
    const int ak = (lane >> 4) * 8;    // k sub-block

    int arow[4];
#pragma unroll
    for (int rt = 0; rt < 4; rt++) {
        int r = r0 + rt * 16 + ar;
        arow[rt] = (r < n) ? r : n - 1;  // clamp (store guarded)
    }
    const unsigned short* Bbase = Wt + (size_t)(w * 64 + ar) * K + ak;

    f32x4 acc[4][4];
#pragma unroll
    for (int rt = 0; rt < 4; rt++)
#pragma unroll
        for (int ct = 0; ct < 4; ct++) acc[rt][ct] = f32x4{0, 0, 0, 0};

#pragma unroll 2
    for (int kk = 0; kk < K; kk += 32) {
        s16x8 a[4], b[4];
#pragma unroll
        for (int rt = 0; rt < 4; rt++)
            a[rt] = *(const s16x8*)(Xb + (size_t)arow[rt] * K + kk + ak);
#pragma unroll
        for (int ct = 0; ct < 4; ct++)
            b[ct] = *(const s16x8*)(Bbase + (size_t)ct * 16 * K + kk);
#pragma unroll
        for (int rt = 0; rt < 4; rt++)
#pragma unroll
            for (int ct = 0; ct < 4; ct++)
                acc[rt][ct] = __builtin_amdgcn_mfma_f32_16x16x32_bf16(a[rt], b[ct], acc[rt][ct], 0, 0, 0);
    }

#pragma unroll
    for (int rt = 0; rt < 4; rt++) {
        int rbase = r0 + rt * 16 + (lane >> 4) * 4;
        float dv[4];
#pragma unroll
        for (int j = 0; j < 4; j++) dv[j] = (rbase + j < n) ? dinv[rbase + j] : 0.0f;
#pragma unroll
        for (int ct = 0; ct < 4; ct++) {
            int c = w * 64 + ct * 16 + ar;
#pragma unroll
            for (int j = 0; j < 4; j++) {
                int r = rbase + j;
                if (r < n) Yb[(size_t)r * HID + c] = f2bf(acc[rt][ct][j] * dv[j]);
            }
        }
    }
}

// ---- gather-aggregate bf16 (wave per node, 8B/lane):
//      out[v] = relu(b + dinv[v] * (H'[v] + sum_in H'[s]))  , H' = (XW)*dinv
__global__ __launch_bounds__(256) void k_aggregate_bf(const unsigned short* __restrict__ Hb,
                                                      const float* __restrict__ dinv,
                                                      const int* __restrict__ row_start,
                                                      const int* __restrict__ csr_src,
                                                      const float* __restrict__ bias,
                                                      unsigned short* __restrict__ O, int n) {
    int v = blockIdx.x * 4 + (threadIdx.x >> 6);
    int lane = threadIdx.x & 63;
    if (v >= n) return;
    const uint2* H2 = (const uint2*)Hb;
    uint2 u = H2[(size_t)v * 64 + lane];  // self term
    float a0 = BFLO(u.x), a1 = BFHI(u.x), a2 = BFLO(u.y), a3 = BFHI(u.y);
    int beg = row_start[v], end = row_start[v + 1];
    int i = beg;
    for (; i + 4 <= end; i += 4) {
        int s0 = csr_src[i + 0];
        int s1 = csr_src[i + 1];
        int s2 = csr_src[i + 2];
        int s3 = csr_src[i + 3];
        uint2 e0 = H2[(size_t)s0 * 64 + lane];
        uint2 e1 = H2[(size_t)s1 * 64 + lane];
        uint2 e2 = H2[(size_t)s2 * 64 + lane];
        uint2 e3 = H2[(size_t)s3 * 64 + lane];
        a0 += (BFLO(e0.x) + BFLO(e1.x)) + (BFLO(e2.x) + BFLO(e3.x));
        a1 += (BFHI(e0.x) + BFHI(e1.x)) + (BFHI(e2.x) + BFHI(e3.x));
        a2 += (BFLO(e0.y) + BFLO(e1.y)) + (BFLO(e2.y) + BFLO(e3.y));
        a3 += (BFHI(e0.y) + BFHI(e1.y)) + (BFHI(e2.y) + BFHI(e3.y));
    }
    for (; i < end; i++) {
        int s = csr_src[i];
        uint2 e0 = H2[(size_t)s * 64 + lane];
        a0 += BFLO(e0.x); a1 += BFHI(e0.x); a2 += BFLO(e0.y); a3 += BFHI(e0.y);
    }
    float dvv = dinv[v];
    float4 bb = ((const float4*)bias)[lane];
    float o0 = fmaxf(fmaf(dvv, a0, bb.x), 0.f);
    float o1 = fmaxf(fmaf(dvv, a1, bb.y), 0.f);
    float o2 = fmaxf(fmaf(dvv, a2, bb.z), 0.f);
    float o3 = fmaxf(fmaf(dvv, a3, bb.w), 0.f);
    uint2 outw;
    outw.x = (unsigned int)f2bf(o0) | ((unsigned int)f2bf(o1) << 16);
    outw.y = (unsigned int)f2bf(o2) | ((unsigned int)f2bf(o3) << 16);
    ((uint2*)O)[(size_t)v * 64 + lane] = outw;
}

// ---------------- mean pool per graph (bf16 in, fp32 out), 4 waves ----------------
__global__ __launch_bounds__(256) void k_pool(const unsigned short* __restrict__ Hb,
                                              const int* __restrict__ batch,
                                              int n, float* __restrict__ G) {
    int g = blockIdx.x;
    int w = threadIdx.x >> 6;
    int lane = threadIdx.x & 63;
    int lo = 0, hi = n;
    while (lo < hi) { int m = (lo + hi) >> 1; if (batch[m] < g) lo = m + 1; else hi = m; }
    int start = lo;
    hi = n;
    while (lo < hi) { int m = (lo + hi) >> 1; if (batch[m] <= g) lo = m + 1; else hi = m; }
    int end = lo;
    const uint2* H2 = (const uint2*)Hb;
    float a0 = 0.f, a1 = 0.f, a2 = 0.f, a3 = 0.f;
    for (int v = start + w; v < end; v += 4) {
        uint2 u = H2[(size_t)v * 64 + lane];
        a0 += BFLO(u.x); a1 += BFHI(u.x); a2 += BFLO(u.y); a3 += BFHI(u.y);
    }
    __shared__ float4 red[4][64];
    red[w][lane] = make_float4(a0, a1, a2, a3);
    __syncthreads();
    if (w == 0) {
        float4 r0 = red[0][lane], r1 = red[1][lane], r2 = red[2][lane], r3 = red[3][lane];
        float inv = 1.0f / fmaxf((float)(end - start), 1.0f);
        float4 o;
        o.x = (r0.x + r1.x + r2.x + r3.x) * inv;
        o.y = (r0.y + r1.y + r2.y + r3.y) * inv;
        o.z = (r0.z + r1.z + r2.z + r3.z) * inv;
        o.w = (r0.w + r1.w + r2.w + r3.w) * inv;
        ((float4*)G)[g * 64 + lane] = o;
    }
}

// ---------------- classifier: sigmoid(relu(G@W3+b3)@W4+b4) ----------------
__global__ __launch_bounds__(128) void k_cls(const float* __restrict__ G,
                                             const float* __restrict__ W3,
                                             const float* __restrict__ b3,
                                             const float* __restrict__ W4,
                                             const float* __restrict__ b4,
                                             float* __restrict__ out) {
    __shared__ float gr[256];
    __shared__ float red[2];
    int g = blockIdx.x, t = threadIdx.x;
    gr[t] = G[g * 256 + t];
    gr[t + 128] = G[g * 256 + t + 128];
    __syncthreads();
    float z = b3[t];
    for (int k = 0; k < 256; k++) z += gr[k] * W3[k * 128 + t];
    z = fmaxf(z, 0.0f);
    float p = z * W4[t];
    for (int off = 32; off; off >>= 1) p += __shfl_down(p, off);
    if ((t & 63) == 0) red[t >> 6] = p;
    __syncthreads();
    if (t == 0) {
        float tot = red[0] + red[1] + b4[0];
        out[g] = 1.0f / (1.0f + expf(-tot));
    }
}

// ---------------- launch ----------------
extern "C" void kernel_launch(void* const* d_in, const int* in_sizes, int n_in,
                              void* d_out, int out_size, void* d_ws, size_t ws_size,
                              hipStream_t stream) {
    const float* x  = (const float*)d_in[0];
    const int*   ei = (const int*)d_in[1];
    const int*   batch = (const int*)d_in[2];
    const float* W1 = (const float*)d_in[3];
    const float* b1 = (const float*)d_in[4];
    const float* W2 = (const float*)d_in[5];
    const float* b2 = (const float*)d_in[6];
    const float* W3 = (const float*)d_in[7];
    const float* b3 = (const float*)d_in[8];
    const float* W4 = (const float*)d_in[9];
    const float* b4 = (const float*)d_in[10];

    const int N = in_sizes[2];       // 50000 nodes
    const int E = in_sizes[1] / 2;   // 800000 edges
    const int G = out_size;          // 128 graphs
    const int NB = (N + 255) / 256;

    char* w = (char*)d_ws;
    float* dinv      = (float*)w;  w += ((size_t)N * 4 + 255) & ~(size_t)255;
    int*   cnt       = (int*)w;    w += ((size_t)N * 4 + 255) & ~(size_t)255;
    int*   excl_tmp  = (int*)w;    w += ((size_t)N * 4 + 255) & ~(size_t)255;
    int*   blksum    = (int*)w;    w += 256 * 4;
    int*   row_start = (int*)w;    w += ((size_t)(N + 1) * 4 + 255) & ~(size_t)255;
    int*   cursor    = (int*)w;    w += ((size_t)N * 4 + 255) & ~(size_t)255;
    int*   csr_src   = (int*)w;    w += ((size_t)E * 4 + 255) & ~(size_t)255;
    unsigned short* xb   = (unsigned short*)w;  w += ((size_t)N * INDIM * 2 + 255) & ~(size_t)255;
    unsigned short* w1t  = (unsigned short*)w;  w += ((size_t)INDIM * HID * 2 + 255) & ~(size_t)255;
    unsigned short* w2t  = (unsigned short*)w;  w += ((size_t)HID * HID * 2 + 255) & ~(size_t)255;
    unsigned short* bufA = (unsigned short*)w;  w += (size_t)N * HID * 2;  // H' (scaled gemm out)
    unsigned short* bufB = (unsigned short*)w;  w += (size_t)N * HID * 2;  // h (post aggregate)
    float* gbuf      = (float*)w;  w += (size_t)G * HID * 4;

    const int* src = ei;
    const int* dst = ei + E;

    // ---- casts / weight transpose ----
    int n4 = N * INDIM / 4;
    k_cast_bf16<<<(n4 + 255) / 256, 256, 0, stream>>>(x, xb, n4);
    k_wt<INDIM><<<HID, INDIM, 0, stream>>>(W1, w1t);
    k_wt<HID><<<HID, HID, 0, stream>>>(W2, w2t);

    // ---- CSR build ----
    hipMemsetAsync(cnt, 0, (size_t)N * 4, stream);
    k_count<<<(E + 255) / 256, 256, 0, stream>>>(dst, E, cnt);
    k_scan_block<<<NB, 256, 0, stream>>>(cnt, excl_tmp, blksum, N);
    k_scan_top<<<1, 256, 0, stream>>>(blksum, NB);
    k_finalize_rows<<<NB, 256, 0, stream>>>(excl_tmp, blksum, cnt, row_start, cursor, dinv, N, E);
    k_fill<<<(E + 255) / 256, 256, 0, stream>>>(src, dst, E, cursor, csr_src);

    const int gemm_blocks = (N + 63) / 64;
    const int agg_blocks  = (N + 3) / 4;

    // ---- layer 1 ----
    k_gemm_mfma<INDIM><<<gemm_blocks, 256, 0, stream>>>(xb, w1t, dinv, bufA, N);
    k_aggregate_bf<<<agg_blocks, 256, 0, stream>>>(bufA, dinv, row_start, csr_src, b1, bufB, N);

    // ---- layer 2 ----
    k_gemm_mfma<HID><<<gemm_blocks, 256, 0, stream>>>(bufB, w2t, dinv, bufA, N);
    k_aggregate_bf<<<agg_blocks, 256, 0, stream>>>(bufA, dinv, row_start, csr_src, b2, bufB, N);

    // ---- pool + classifier ----
    k_pool<<<G, 256, 0, stream>>>(bufB, batch, N, gbuf);
    k_cls<<<G, 128, 0, stream>>>(gbuf, W3, b3, W4, b4, (float*)d_out);
}

// Round 6
// 313.157 us; speedup vs baseline: 18.5480x; 1.1289x over previous
//
#include <hip/hip_runtime.h>
#include <math.h>

#define HID 256
#define INDIM 128

typedef short s16x8 __attribute__((ext_vector_type(8)));
typedef float f32x4 __attribute__((ext_vector_type(4)));

// ---- bf16 helpers (RNE, finite inputs) ----
static __device__ __forceinline__ unsigned short f2bf(float f) {
    unsigned int u = __float_as_uint(f);
    unsigned int r = (u + 0x7fffu + ((u >> 16) & 1u)) >> 16;
    return (unsigned short)r;
}
#define BFLO(x) __uint_as_float((x) << 16)
#define BFHI(x) __uint_as_float((x) & 0xffff0000u)

#define ACC8(a, u)                                  \
    do {                                            \
        a[0] += BFLO((u).x); a[1] += BFHI((u).x);   \
        a[2] += BFLO((u).y); a[3] += BFHI((u).y);   \
        a[4] += BFLO((u).z); a[5] += BFHI((u).z);   \
        a[6] += BFLO((u).w); a[7] += BFHI((u).w);   \
    } while (0)

// ---------------- in-degree count ----------------
__global__ void k_count(const int* __restrict__ dst, int E, int* cnt) {
    int e = blockIdx.x * blockDim.x + threadIdx.x;
    if (e < E) atomicAdd(&cnt[dst[e]], 1);
}

// ---------------- 2-level exclusive scan ----------------
__global__ __launch_bounds__(256) void k_scan_block(const int* __restrict__ cnt,
                                                    int* excl_tmp, int* blksum, int n) {
    __shared__ int sm[256];
    int t = threadIdx.x;
    int i = blockIdx.x * 256 + t;
    int c = (i < n) ? cnt[i] : 0;
    sm[t] = c;
    __syncthreads();
    for (int off = 1; off < 256; off <<= 1) {
        int v = (t >= off) ? sm[t - off] : 0;
        __syncthreads();
        sm[t] += v;
        __syncthreads();
    }
    if (i < n) excl_tmp[i] = sm[t] - c;
    if (t == 255) blksum[blockIdx.x] = sm[255];
}

__global__ __launch_bounds__(256) void k_scan_top(int* blksum, int nb) {
    __shared__ int sm[256];
    int t = threadIdx.x;
    int c = (t < nb) ? blksum[t] : 0;
    sm[t] = c;
    __syncthreads();
    for (int off = 1; off < 256; off <<= 1) {
        int v = (t >= off) ? sm[t - off] : 0;
        __syncthreads();
        sm[t] += v;
        __syncthreads();
    }
    if (t < nb) blksum[t] = sm[t] - c;
}

// rows + cursor + dinv in one pass
__global__ __launch_bounds__(256) void k_finalize_rows(const int* __restrict__ excl_tmp,
                                                       const int* __restrict__ blksum,
                                                       const int* __restrict__ cnt,
                                                       int* row_start, int* cursor,
                                                       float* dinv, int n, int E) {
    int i = blockIdx.x * 256 + threadIdx.x;
    if (i < n) {
        int r = excl_tmp[i] + blksum[blockIdx.x];
        row_start[i] = r;
        cursor[i] = r;
        dinv[i] = rsqrtf((float)(cnt[i] + 1));
    }
    if (i == 0) row_start[n] = E;
}

// ---------------- fill CSR ----------------
__global__ void k_fill(const int* __restrict__ src, const int* __restrict__ dst,
                       int E, int* cursor, int* csr_src) {
    int e = blockIdx.x * blockDim.x + threadIdx.x;
    if (e < E) {
        int p = atomicAdd(&cursor[dst[e]], 1);
        csr_src[p] = src[e];
    }
}

// ---------------- cast + per-row dinv scale: xs = bf16(x * dinv[row]) -------
__global__ void k_cast_scale(const float* __restrict__ x, const float* __restrict__ dinv,
                             unsigned short* __restrict__ out, int n4) {
    int i = blockIdx.x * blockDim.x + threadIdx.x;  // float4 index; 32 per row
    if (i < n4) {
        float dv = dinv[i >> 5];
        float4 v = ((const float4*)x)[i];
        ushort4 o;
        o.x = f2bf(v.x * dv); o.y = f2bf(v.y * dv);
        o.z = f2bf(v.z * dv); o.w = f2bf(v.w * dv);
        ((ushort4*)out)[i] = o;
    }
}

// Wt[c][k] = bf16(W[k][c]); launch <<<256, K>>>
template <int K>
__global__ void k_wt(const float* __restrict__ W, unsigned short* __restrict__ Wt) {
    int c = blockIdx.x;
    int t = threadIdx.x;
    Wt[(size_t)c * K + t] = f2bf(W[(size_t)t * HID + c]);
}

// ---- MFMA GEMM: Yb[n,HID](bf16) = epi(Xb[n,K](bf16) @ W)
// EPI 0: *dinv[row]   EPI 1: relu(+bias[col])
// block: 64 rows x 256 cols; wave: 64x64 = 4 row-tiles x 4 col-tiles
template <int K, int EPI>
__global__ __launch_bounds__(256) void k_gemm_mfma(const unsigned short* __restrict__ Xb,
                                                   const unsigned short* __restrict__ Wt,
                                                   const float* __restrict__ epi,
                                                   unsigned short* __restrict__ Yb, int n) {
    const int r0 = blockIdx.x * 64;
    const int w = threadIdx.x >> 6;
    const int lane = threadIdx.x & 63;
    const int ar = lane & 15;          // A row within tile / B col within tile
    const int ak = (lane >> 4) * 8;    // k sub-block

    int arow[4];
#pragma unroll
    for (int rt = 0; rt < 4; rt++) {
        int r = r0 + rt * 16 + ar;
        arow[rt] = (r < n) ? r : n - 1;  // clamp (store guarded)
    }
    const unsigned short* Bbase = Wt + (size_t)(w * 64 + ar) * K + ak;

    f32x4 acc[4][4];
#pragma unroll
    for (int rt = 0; rt < 4; rt++)
#pragma unroll
        for (int ct = 0; ct < 4; ct++) acc[rt][ct] = f32x4{0, 0, 0, 0};

#pragma unroll 2
    for (int kk = 0; kk < K; kk += 32) {
        s16x8 a[4], b[4];
#pragma unroll
        for (int rt = 0; rt < 4; rt++)
            a[rt] = *(const s16x8*)(Xb + (size_t)arow[rt] * K + kk + ak);
#pragma unroll
        for (int ct = 0; ct < 4; ct++)
            b[ct] = *(const s16x8*)(Bbase + (size_t)ct * 16 * K + kk);
#pragma unroll
        for (int rt = 0; rt < 4; rt++)
#pragma unroll
            for (int ct = 0; ct < 4; ct++)
                acc[rt][ct] = __builtin_amdgcn_mfma_f32_16x16x32_bf16(a[rt], b[ct], acc[rt][ct], 0, 0, 0);
    }

#pragma unroll
    for (int rt = 0; rt < 4; rt++) {
        int rbase = r0 + rt * 16 + (lane >> 4) * 4;
        if constexpr (EPI == 0) {
            float dv[4];
#pragma unroll
            for (int j = 0; j < 4; j++) dv[j] = (rbase + j < n) ? epi[rbase + j] : 0.0f;
#pragma unroll
            for (int ct = 0; ct < 4; ct++) {
                int c = w * 64 + ct * 16 + ar;
#pragma unroll
                for (int j = 0; j < 4; j++) {
                    int r = rbase + j;
                    if (r < n) Yb[(size_t)r * HID + c] = f2bf(acc[rt][ct][j] * dv[j]);
                }
            }
        } else {
#pragma unroll
            for (int ct = 0; ct < 4; ct++) {
                int c = w * 64 + ct * 16 + ar;
                float bc = epi[c];
#pragma unroll
                for (int j = 0; j < 4; j++) {
                    int r = rbase + j;
                    if (r < n) Yb[(size_t)r * HID + c] = f2bf(fmaxf(acc[rt][ct][j] + bc, 0.0f));
                }
            }
        }
    }
}

// ---- gather-aggregate bf16, 16B/lane, D channels.
//      BIASRELU=0: out[v] = bf16(dinv[v] * (H[v] + sum_in H[s]))
//      BIASRELU=1: out[v] = bf16(relu(b + dinv[v] * (H[v] + sum_in H[s])))
// LPR = D/8 lanes per row; EPW = 64/LPR edges per wave-iteration; unroll 4.
template <int D, bool BIASRELU>
__global__ __launch_bounds__(256) void k_agg(const unsigned short* __restrict__ Hb,
                                             const float* __restrict__ dinv,
                                             const int* __restrict__ row_start,
                                             const int* __restrict__ csr_src,
                                             const float* __restrict__ bias,
                                             unsigned short* __restrict__ O, int n) {
    constexpr int LPR = D / 8;      // uint4 chunks per row
    constexpr int EPW = 64 / LPR;
    const int v = blockIdx.x * 4 + (threadIdx.x >> 6);
    const int lane = threadIdx.x & 63;
    const int sub = lane / LPR;
    const int li = lane % LPR;
    if (v >= n) return;
    const uint4* H4 = (const uint4*)Hb;
    float a[8] = {0, 0, 0, 0, 0, 0, 0, 0};
    const int beg = row_start[v], end = row_start[v + 1];
    int i = beg + sub;
    for (; i + 3 * EPW < end; i += 4 * EPW) {
        int s0 = csr_src[i];
        int s1 = csr_src[i + EPW];
        int s2 = csr_src[i + 2 * EPW];
        int s3 = csr_src[i + 3 * EPW];
        uint4 u0 = H4[(size_t)s0 * LPR + li];
        uint4 u1 = H4[(size_t)s1 * LPR + li];
        uint4 u2 = H4[(size_t)s2 * LPR + li];
        uint4 u3 = H4[(size_t)s3 * LPR + li];
        ACC8(a, u0); ACC8(a, u1); ACC8(a, u2); ACC8(a, u3);
    }
    for (; i < end; i += EPW) {
        uint4 u = H4[(size_t)csr_src[i] * LPR + li];
        ACC8(a, u);
    }
    // combine partial sums across edge-slots (butterfly)
#pragma unroll
    for (int k = 0; k < 8; k++) {
        if constexpr (LPR <= 16) a[k] += __shfl_xor(a[k], 16);
        a[k] += __shfl_xor(a[k], 32);
    }
    if (lane < LPR) {
        uint4 us = H4[(size_t)v * LPR + li];  // self term
        ACC8(a, us);
        float dv = dinv[v];
        float o[8];
        if constexpr (BIASRELU) {
            const float4* B4 = (const float4*)bias;
            float4 b0 = B4[li * 2], b1 = B4[li * 2 + 1];
            o[0] = fmaxf(fmaf(dv, a[0], b0.x), 0.f);
            o[1] = fmaxf(fmaf(dv, a[1], b0.y), 0.f);
            o[2] = fmaxf(fmaf(dv, a[2], b0.z), 0.f);
            o[3] = fmaxf(fmaf(dv, a[3], b0.w), 0.f);
            o[4] = fmaxf(fmaf(dv, a[4], b1.x), 0.f);
            o[5] = fmaxf(fmaf(dv, a[5], b1.y), 0.f);
            o[6] = fmaxf(fmaf(dv, a[6], b1.z), 0.f);
            o[7] = fmaxf(fmaf(dv, a[7], b1.w), 0.f);
        } else {
#pragma unroll
            for (int k = 0; k < 8; k++) o[k] = dv * a[k];
        }
        uint4 ow;
        ow.x = (unsigned int)f2bf(o[0]) | ((unsigned int)f2bf(o[1]) << 16);
        ow.y = (unsigned int)f2bf(o[2]) | ((unsigned int)f2bf(o[3]) << 16);
        ow.z = (unsigned int)f2bf(o[4]) | ((unsigned int)f2bf(o[5]) << 16);
        ow.w = (unsigned int)f2bf(o[6]) | ((unsigned int)f2bf(o[7]) << 16);
        ((uint4*)O)[(size_t)v * LPR + li] = ow;
    }
}

// ---------------- mean pool per graph (bf16 in, fp32 out) ----------------
// 4 waves; each wave: half-wave per node (16B/lane), 8 nodes in flight per block.
__global__ __launch_bounds__(256) void k_pool(const unsigned short* __restrict__ Hb,
                                              const int* __restrict__ batch,
                                              int n, float* __restrict__ G) {
    int g = blockIdx.x;
    int w = threadIdx.x >> 6;
    int lane = threadIdx.x & 63;
    int sub = lane >> 5;
    int li = lane & 31;
    int lo = 0, hi = n;
    while (lo < hi) { int m = (lo + hi) >> 1; if (batch[m] < g) lo = m + 1; else hi = m; }
    int start = lo;
    hi = n;
    while (lo < hi) { int m = (lo + hi) >> 1; if (batch[m] <= g) lo = m + 1; else hi = m; }
    int end = lo;
    const uint4* H4 = (const uint4*)Hb;
    float a[8] = {0, 0, 0, 0, 0, 0, 0, 0};
    for (int v = start + w * 2 + sub; v < end; v += 8) {
        uint4 u = H4[(size_t)v * 32 + li];
        ACC8(a, u);
    }
#pragma unroll
    for (int k = 0; k < 8; k++) a[k] += __shfl_xor(a[k], 32);
    __shared__ float red[4][32][8];
    if (lane < 32) {
#pragma unroll
        for (int k = 0; k < 8; k++) red[w][li][k] = a[k];
    }
    __syncthreads();
    if (w == 0 && lane < 32) {
        float inv = 1.0f / fmaxf((float)(end - start), 1.0f);
        float o[8];
#pragma unroll
        for (int k = 0; k < 8; k++)
            o[k] = (red[0][li][k] + red[1][li][k] + red[2][li][k] + red[3][li][k]) * inv;
        float4* Gp = (float4*)(G + (size_t)g * HID + li * 8);
        Gp[0] = make_float4(o[0], o[1], o[2], o[3]);
        Gp[1] = make_float4(o[4], o[5], o[6], o[7]);
    }
}

// ---------------- classifier: sigmoid(relu(G@W3+b3)@W4+b4) ----------------
__global__ __launch_bounds__(128) void k_cls(const float* __restrict__ G,
                                             const float* __restrict__ W3,
                                             const float* __restrict__ b3,
                                             const float* __restrict__ W4,
                                             const float* __restrict__ b4,
                                             float* __restrict__ out) {
    __shared__ float gr[256];
    __shared__ float red[2];
    int g = blockIdx.x, t = threadIdx.x;
    gr[t] = G[g * 256 + t];
    gr[t + 128] = G[g * 256 + t + 128];
    __syncthreads();
    float z = b3[t];
    for (int k = 0; k < 256; k++) z += gr[k] * W3[k * 128 + t];
    z = fmaxf(z, 0.0f);
    float p = z * W4[t];
    for (int off = 32; off; off >>= 1) p += __shfl_down(p, off);
    if ((t & 63) == 0) red[t >> 6] = p;
    __syncthreads();
    if (t == 0) {
        float tot = red[0] + red[1] + b4[0];
        out[g] = 1.0f / (1.0f + expf(-tot));
    }
}

// ---------------- launch ----------------
extern "C" void kernel_launch(void* const* d_in, const int* in_sizes, int n_in,
                              void* d_out, int out_size, void* d_ws, size_t ws_size,
                              hipStream_t stream) {
    const float* x  = (const float*)d_in[0];
    const int*   ei = (const int*)d_in[1];
    const int*   batch = (const int*)d_in[2];
    const float* W1 = (const float*)d_in[3];
    const float* b1 = (const float*)d_in[4];
    const float* W2 = (const float*)d_in[5];
    const float* b2 = (const float*)d_in[6];
    const float* W3 = (const float*)d_in[7];
    const float* b3 = (const float*)d_in[8];
    const float* W4 = (const float*)d_in[9];
    const float* b4 = (const float*)d_in[10];

    const int N = in_sizes[2];       // 50000 nodes
    const int E = in_sizes[1] / 2;   // 800000 edges
    const int G = out_size;          // 128 graphs
    const int NB = (N + 255) / 256;

    char* w = (char*)d_ws;
    float* dinv      = (float*)w;  w += ((size_t)N * 4 + 255) & ~(size_t)255;
    int*   cnt       = (int*)w;    w += ((size_t)N * 4 + 255) & ~(size_t)255;
    int*   excl_tmp  = (int*)w;    w += ((size_t)N * 4 + 255) & ~(size_t)255;
    int*   blksum    = (int*)w;    w += 256 * 4;
    int*   row_start = (int*)w;    w += ((size_t)(N + 1) * 4 + 255) & ~(size_t)255;
    int*   cursor    = (int*)w;    w += ((size_t)N * 4 + 255) & ~(size_t)255;
    int*   csr_src   = (int*)w;    w += ((size_t)E * 4 + 255) & ~(size_t)255;
    unsigned short* xb   = (unsigned short*)w;  w += ((size_t)N * INDIM * 2 + 255) & ~(size_t)255;
    unsigned short* w1t  = (unsigned short*)w;  w += ((size_t)INDIM * HID * 2 + 255) & ~(size_t)255;
    unsigned short* w2t  = (unsigned short*)w;  w += ((size_t)HID * HID * 2 + 255) & ~(size_t)255;
    unsigned short* bufA = (unsigned short*)w;  w += (size_t)N * HID * 2;  // t1 / H2'
    unsigned short* bufB = (unsigned short*)w;  w += (size_t)N * HID * 2;  // h1 / h2
    float* gbuf      = (float*)w;  w += (size_t)G * HID * 4;

    const int* src = ei;
    const int* dst = ei + E;

    // ---- weight transposes (independent of graph) ----
    k_wt<INDIM><<<HID, INDIM, 0, stream>>>(W1, w1t);
    k_wt<HID><<<HID, HID, 0, stream>>>(W2, w2t);

    // ---- CSR build + dinv ----
    hipMemsetAsync(cnt, 0, (size_t)N * 4, stream);
    k_count<<<(E + 255) / 256, 256, 0, stream>>>(dst, E, cnt);
    k_scan_block<<<NB, 256, 0, stream>>>(cnt, excl_tmp, blksum, N);
    k_scan_top<<<1, 256, 0, stream>>>(blksum, NB);
    k_finalize_rows<<<NB, 256, 0, stream>>>(excl_tmp, blksum, cnt, row_start, cursor, dinv, N, E);
    k_fill<<<(E + 255) / 256, 256, 0, stream>>>(src, dst, E, cursor, csr_src);

    // ---- scaled cast: xs = bf16(x * dinv[row]) ----
    int n4 = N * INDIM / 4;
    k_cast_scale<<<(n4 + 255) / 256, 256, 0, stream>>>(x, dinv, xb, n4);

    const int gemm_blocks = (N + 63) / 64;
    const int agg_blocks  = (N + 3) / 4;

    // ---- layer 1: aggregate in 128-dim, then GEMM(+bias+relu) ----
    k_agg<INDIM, false><<<agg_blocks, 256, 0, stream>>>(xb, dinv, row_start, csr_src, b1, bufA, N);
    k_gemm_mfma<INDIM, 1><<<gemm_blocks, 256, 0, stream>>>(bufA, w1t, b1, bufB, N);

    // ---- layer 2: GEMM(*dinv), then aggregate(+bias+relu) in 256-dim ----
    k_gemm_mfma<HID, 0><<<gemm_blocks, 256, 0, stream>>>(bufB, w2t, dinv, bufA, N);
    k_agg<HID, true><<<agg_blocks, 256, 0, stream>>>(bufA, dinv, row_start, csr_src, b2, bufB, N);

    // ---- pool + classifier ----
    k_pool<<<G, 256, 0, stream>>>(bufB, batch, N, gbuf);
    k_cls<<<G, 128, 0, stream>>>(gbuf, W3, b3, W4, b4, (float*)d_out);
}

// Round 7
// 304.644 us; speedup vs baseline: 19.0663x; 1.0279x over previous
//
#include <hip/hip_runtime.h>
#include <math.h>

#define HID 256
#define INDIM 128

typedef short s16x8 __attribute__((ext_vector_type(8)));
typedef float f32x4 __attribute__((ext_vector_type(4)));
typedef float f32x2 __attribute__((ext_vector_type(2)));

// ---- bf16 helpers (RNE, finite inputs) ----
static __device__ __forceinline__ unsigned short f2bf(float f) {
    unsigned int u = __float_as_uint(f);
    unsigned int r = (u + 0x7fffu + ((u >> 16) & 1u)) >> 16;
    return (unsigned short)r;
}

// ---- fp8 e4m3 decode: one 32-bit word -> 4 floats, accumulate ----
#define DECW(a, base, w)                                                  \
    do {                                                                  \
        f32x2 p0 = __builtin_amdgcn_cvt_pk_f32_fp8((int)(w), false);      \
        f32x2 p1 = __builtin_amdgcn_cvt_pk_f32_fp8((int)(w), true);       \
        a[(base) + 0] += p0[0]; a[(base) + 1] += p0[1];                   \
        a[(base) + 2] += p1[0]; a[(base) + 3] += p1[1];                   \
    } while (0)
#define DEC16(a, u)                                                       \
    do { DECW(a, 0, (u).x); DECW(a, 4, (u).y);                            \
         DECW(a, 8, (u).z); DECW(a, 12, (u).w); } while (0)

// ---------------- in-degree count ----------------
__global__ void k_count(const int* __restrict__ dst, int E, int* cnt) {
    int e = blockIdx.x * blockDim.x + threadIdx.x;
    if (e < E) atomicAdd(&cnt[dst[e]], 1);
}

// ---------------- 2-level exclusive scan ----------------
__global__ __launch_bounds__(256) void k_scan_block(const int* __restrict__ cnt,
                                                    int* excl_tmp, int* blksum, int n) {
    __shared__ int sm[256];
    int t = threadIdx.x;
    int i = blockIdx.x * 256 + t;
    int c = (i < n) ? cnt[i] : 0;
    sm[t] = c;
    __syncthreads();
    for (int off = 1; off < 256; off <<= 1) {
        int v = (t >= off) ? sm[t - off] : 0;
        __syncthreads();
        sm[t] += v;
        __syncthreads();
    }
    if (i < n) excl_tmp[i] = sm[t] - c;
    if (t == 255) blksum[blockIdx.x] = sm[255];
}

__global__ __launch_bounds__(256) void k_scan_top(int* blksum, int nb) {
    __shared__ int sm[256];
    int t = threadIdx.x;
    int c = (t < nb) ? blksum[t] : 0;
    sm[t] = c;
    __syncthreads();
    for (int off = 1; off < 256; off <<= 1) {
        int v = (t >= off) ? sm[t - off] : 0;
        __syncthreads();
        sm[t] += v;
        __syncthreads();
    }
    if (t < nb) blksum[t] = sm[t] - c;
}

// rows + cursor + dinv in one pass
__global__ __launch_bounds__(256) void k_finalize_rows(const int* __restrict__ excl_tmp,
                                                       const int* __restrict__ blksum,
                                                       const int* __restrict__ cnt,
                                                       int* row_start, int* cursor,
                                                       float* dinv, int n, int E) {
    int i = blockIdx.x * 256 + threadIdx.x;
    if (i < n) {
        int r = excl_tmp[i] + blksum[blockIdx.x];
        row_start[i] = r;
        cursor[i] = r;
        dinv[i] = rsqrtf((float)(cnt[i] + 1));
    }
    if (i == 0) row_start[n] = E;
}

// ---------------- fill CSR ----------------
__global__ void k_fill(const int* __restrict__ src, const int* __restrict__ dst,
                       int E, int* cursor, int* csr_src) {
    int e = blockIdx.x * blockDim.x + threadIdx.x;
    if (e < E) {
        int p = atomicAdd(&cursor[dst[e]], 1);
        csr_src[p] = src[e];
    }
}

// ---------------- cast + dinv scale to fp8: xq = fp8(x * dinv[row]) -------
// one thread = 4 channels (one float4 -> one u32 of 4 fp8)
__global__ void k_cast_q(const float* __restrict__ x, const float* __restrict__ dinv,
                         unsigned int* __restrict__ out, int nw) {
    int i = blockIdx.x * blockDim.x + threadIdx.x;  // word idx; INDIM/4=32 per row
    if (i < nw) {
        float dv = dinv[i >> 5];
        float4 v = ((const float4*)x)[i];
        int w0 = __builtin_amdgcn_cvt_pk_fp8_f32(v.x * dv, v.y * dv, 0, false);
        w0 = __builtin_amdgcn_cvt_pk_fp8_f32(v.z * dv, v.w * dv, w0, true);
        out[i] = (unsigned int)w0;
    }
}

// Wt[c][k] = bf16(W[k][c]); launch <<<256, K>>>
template <int K>
__global__ void k_wt(const float* __restrict__ W, unsigned short* __restrict__ Wt) {
    int c = blockIdx.x;
    int t = threadIdx.x;
    Wt[(size_t)c * K + t] = f2bf(W[(size_t)t * HID + c]);
}

// ---- MFMA GEMM: Y[n,HID] = epi(Xb[n,K](bf16) @ W)
// EPI 1: relu(+bias[col]) -> bf16    EPI 2: *dinv[row] -> fp8
// block: 64 rows x 256 cols; wave: 64x64 = 4 row-tiles x 4 col-tiles
template <int K, int EPI>
__global__ __launch_bounds__(256) void k_gemm_mfma(const unsigned short* __restrict__ Xb,
                                                   const unsigned short* __restrict__ Wt,
                                                   const float* __restrict__ epi,
                                                   void* __restrict__ Yout, int n) {
    const int r0 = blockIdx.x * 64;
    const int w = threadIdx.x >> 6;
    const int lane = threadIdx.x & 63;
    const int ar = lane & 15;
    const int ak = (lane >> 4) * 8;

    int arow[4];
#pragma unroll
    for (int rt = 0; rt < 4; rt++) {
        int r = r0 + rt * 16 + ar;
        arow[rt] = (r < n) ? r : n - 1;  // clamp (store guarded)
    }
    const unsigned short* Bbase = Wt + (size_t)(w * 64 + ar) * K + ak;

    f32x4 acc[4][4];
#pragma unroll
    for (int rt = 0; rt < 4; rt++)
#pragma unroll
        for (int ct = 0; ct < 4; ct++) acc[rt][ct] = f32x4{0, 0, 0, 0};

#pragma unroll 2
    for (int kk = 0; kk < K; kk += 32) {
        s16x8 a[4], b[4];
#pragma unroll
        for (int rt = 0; rt < 4; rt++)
            a[rt] = *(const s16x8*)(Xb + (size_t)arow[rt] * K + kk + ak);
#pragma unroll
        for (int ct = 0; ct < 4; ct++)
            b[ct] = *(const s16x8*)(Bbase + (size_t)ct * 16 * K + kk);
#pragma unroll
        for (int rt = 0; rt < 4; rt++)
#pragma unroll
            for (int ct = 0; ct < 4; ct++)
                acc[rt][ct] = __builtin_amdgcn_mfma_f32_16x16x32_bf16(a[rt], b[ct], acc[rt][ct], 0, 0, 0);
    }

#pragma unroll
    for (int rt = 0; rt < 4; rt++) {
        int rbase = r0 + rt * 16 + (lane >> 4) * 4;
        if constexpr (EPI == 1) {
            unsigned short* Yb = (unsigned short*)Yout;
#pragma unroll
            for (int ct = 0; ct < 4; ct++) {
                int c = w * 64 + ct * 16 + ar;
                float bc = epi[c];
#pragma unroll
                for (int j = 0; j < 4; j++) {
                    int r = rbase + j;
                    if (r < n) Yb[(size_t)r * HID + c] = f2bf(fmaxf(acc[rt][ct][j] + bc, 0.0f));
                }
            }
        } else {
            unsigned char* Yq = (unsigned char*)Yout;
            float dv[4];
#pragma unroll
            for (int j = 0; j < 4; j++) dv[j] = (rbase + j < n) ? epi[rbase + j] : 0.0f;
#pragma unroll
            for (int ct = 0; ct < 4; ct++) {
                int c = w * 64 + ct * 16 + ar;
#pragma unroll
                for (int j = 0; j < 4; j++) {
                    int r = rbase + j;
                    if (r < n) {
                        float f = acc[rt][ct][j] * dv[j];
                        int e = __builtin_amdgcn_cvt_pk_fp8_f32(f, f, 0, false);
                        Yq[(size_t)r * HID + c] = (unsigned char)(e & 0xff);
                    }
                }
            }
        }
    }
}

// ---- gather-aggregate fp8 -> bf16, 16B/lane = 16 channels/lane.
//      BIASRELU=0: out[v] = bf16(dinv[v] * (Hq[v] + sum_in Hq[s]))
//      BIASRELU=1: out[v] = bf16(relu(b + dinv[v] * (Hq[v] + sum_in Hq[s])))
// LPR = D/16 uint4-chunks per row; EPW = 64/LPR edges per wave-iteration.
template <int D, bool BIASRELU>
__global__ __launch_bounds__(256) void k_agg_q(const unsigned char* __restrict__ Hq,
                                               const float* __restrict__ dinv,
                                               const int* __restrict__ row_start,
                                               const int* __restrict__ csr_src,
                                               const float* __restrict__ bias,
                                               unsigned short* __restrict__ O, int n) {
    constexpr int LPR = D / 16;
    constexpr int EPW = 64 / LPR;
    const int v = blockIdx.x * 4 + (threadIdx.x >> 6);
    const int lane = threadIdx.x & 63;
    const int sub = lane / LPR;
    const int li = lane % LPR;
    if (v >= n) return;
    const uint4* H4 = (const uint4*)Hq;
    float a[16];
#pragma unroll
    for (int k = 0; k < 16; k++) a[k] = 0.f;
    const int beg = row_start[v], end = row_start[v + 1];
    int i = beg + sub;
    for (; i + 3 * EPW < end; i += 4 * EPW) {
        int s0 = csr_src[i];
        int s1 = csr_src[i + EPW];
        int s2 = csr_src[i + 2 * EPW];
        int s3 = csr_src[i + 3 * EPW];
        uint4 u0 = H4[(size_t)s0 * LPR + li];
        uint4 u1 = H4[(size_t)s1 * LPR + li];
        uint4 u2 = H4[(size_t)s2 * LPR + li];
        uint4 u3 = H4[(size_t)s3 * LPR + li];
        DEC16(a, u0); DEC16(a, u1); DEC16(a, u2); DEC16(a, u3);
    }
    for (; i < end; i += EPW) {
        uint4 u = H4[(size_t)csr_src[i] * LPR + li];
        DEC16(a, u);
    }
    // combine edge-slot partial sums (butterfly over lane bits >= log2(LPR))
#pragma unroll
    for (int off = LPR; off < 64; off <<= 1)
#pragma unroll
        for (int k = 0; k < 16; k++) a[k] += __shfl_xor(a[k], off);

    if (lane < LPR) {
        uint4 us = H4[(size_t)v * LPR + li];  // self term
        DEC16(a, us);
        float dv = dinv[v];
        float o[16];
        if constexpr (BIASRELU) {
            const float4* B4 = (const float4*)bias;
#pragma unroll
            for (int q = 0; q < 4; q++) {
                float4 bb = B4[li * 4 + q];
                o[q * 4 + 0] = fmaxf(fmaf(dv, a[q * 4 + 0], bb.x), 0.f);
                o[q * 4 + 1] = fmaxf(fmaf(dv, a[q * 4 + 1], bb.y), 0.f);
                o[q * 4 + 2] = fmaxf(fmaf(dv, a[q * 4 + 2], bb.z), 0.f);
                o[q * 4 + 3] = fmaxf(fmaf(dv, a[q * 4 + 3], bb.w), 0.f);
            }
        } else {
#pragma unroll
            for (int k = 0; k < 16; k++) o[k] = dv * a[k];
        }
        uint4 ow0, ow1;
        ow0.x = (unsigned int)f2bf(o[0]) | ((unsigned int)f2bf(o[1]) << 16);
        ow0.y = (unsigned int)f2bf(o[2]) | ((unsigned int)f2bf(o[3]) << 16);
        ow0.z = (unsigned int)f2bf(o[4]) | ((unsigned int)f2bf(o[5]) << 16);
        ow0.w = (unsigned int)f2bf(o[6]) | ((unsigned int)f2bf(o[7]) << 16);
        ow1.x = (unsigned int)f2bf(o[8]) | ((unsigned int)f2bf(o[9]) << 16);
        ow1.y = (unsigned int)f2bf(o[10]) | ((unsigned int)f2bf(o[11]) << 16);
        ow1.z = (unsigned int)f2bf(o[12]) | ((unsigned int)f2bf(o[13]) << 16);
        ow1.w = (unsigned int)f2bf(o[14]) | ((unsigned int)f2bf(o[15]) << 16);
        uint4* Op = (uint4*)O + (size_t)v * (2 * LPR) + li * 2;
        Op[0] = ow0;
        Op[1] = ow1;
    }
}

#define BFLO(x) __uint_as_float((x) << 16)
#define BFHI(x) __uint_as_float((x) & 0xffff0000u)
#define ACC8(a, u)                                  \
    do {                                            \
        a[0] += BFLO((u).x); a[1] += BFHI((u).x);   \
        a[2] += BFLO((u).y); a[3] += BFHI((u).y);   \
        a[4] += BFLO((u).z); a[5] += BFHI((u).z);   \
        a[6] += BFLO((u).w); a[7] += BFHI((u).w);   \
    } while (0)

// ---------------- mean pool per graph (bf16 in, fp32 out) ----------------
__global__ __launch_bounds__(256) void k_pool(const unsigned short* __restrict__ Hb,
                                              const int* __restrict__ batch,
                                              int n, float* __restrict__ G) {
    int g = blockIdx.x;
    int w = threadIdx.x >> 6;
    int lane = threadIdx.x & 63;
    int sub = lane >> 5;
    int li = lane & 31;
    int lo = 0, hi = n;
    while (lo < hi) { int m = (lo + hi) >> 1; if (batch[m] < g) lo = m + 1; else hi = m; }
    int start = lo;
    hi = n;
    while (lo < hi) { int m = (lo + hi) >> 1; if (batch[m] <= g) lo = m + 1; else hi = m; }
    int end = lo;
    const uint4* H4 = (const uint4*)Hb;
    float a[8] = {0, 0, 0, 0, 0, 0, 0, 0};
    for (int v = start + w * 2 + sub; v < end; v += 8) {
        uint4 u = H4[(size_t)v * 32 + li];
        ACC8(a, u);
    }
#pragma unroll
    for (int k = 0; k < 8; k++) a[k] += __shfl_xor(a[k], 32);
    __shared__ float red[4][32][8];
    if (lane < 32) {
#pragma unroll
        for (int k = 0; k < 8; k++) red[w][li][k] = a[k];
    }
    __syncthreads();
    if (w == 0 && lane < 32) {
        float inv = 1.0f / fmaxf((float)(end - start), 1.0f);
        float o[8];
#pragma unroll
        for (int k = 0; k < 8; k++)
            o[k] = (red[0][li][k] + red[1][li][k] + red[2][li][k] + red[3][li][k]) * inv;
        float4* Gp = (float4*)(G + (size_t)g * HID + li * 8);
        Gp[0] = make_float4(o[0], o[1], o[2], o[3]);
        Gp[1] = make_float4(o[4], o[5], o[6], o[7]);
    }
}

// ---------------- classifier: sigmoid(relu(G@W3+b3)@W4+b4) ----------------
__global__ __launch_bounds__(128) void k_cls(const float* __restrict__ G,
                                             const float* __restrict__ W3,
                                             const float* __restrict__ b3,
                                             const float* __restrict__ W4,
                                             const float* __restrict__ b4,
                                             float* __restrict__ out) {
    __shared__ float gr[256];
    __shared__ float red[2];
    int g = blockIdx.x, t = threadIdx.x;
    gr[t] = G[g * 256 + t];
    gr[t + 128] = G[g * 256 + t + 128];
    __syncthreads();
    float z = b3[t];
    for (int k = 0; k < 256; k++) z += gr[k] * W3[k * 128 + t];
    z = fmaxf(z, 0.0f);
    float p = z * W4[t];
    for (int off = 32; off; off >>= 1) p += __shfl_down(p, off);
    if ((t & 63) == 0) red[t >> 6] = p;
    __syncthreads();
    if (t == 0) {
        float tot = red[0] + red[1] + b4[0];
        out[g] = 1.0f / (1.0f + expf(-tot));
    }
}

// ---------------- launch ----------------
extern "C" void kernel_launch(void* const* d_in, const int* in_sizes, int n_in,
                              void* d_out, int out_size, void* d_ws, size_t ws_size,
                              hipStream_t stream) {
    const float* x  = (const float*)d_in[0];
    const int*   ei = (const int*)d_in[1];
    const int*   batch = (const int*)d_in[2];
    const float* W1 = (const float*)d_in[3];
    const float* b1 = (const float*)d_in[4];
    const float* W2 = (const float*)d_in[5];
    const float* b2 = (const float*)d_in[6];
    const float* W3 = (const float*)d_in[7];
    const float* b3 = (const float*)d_in[8];
    const float* W4 = (const float*)d_in[9];
    const float* b4 = (const float*)d_in[10];

    const int N = in_sizes[2];       // 50000 nodes
    const int E = in_sizes[1] / 2;   // 800000 edges
    const int G = out_size;          // 128 graphs
    const int NB = (N + 255) / 256;

    char* w = (char*)d_ws;
    float* dinv      = (float*)w;  w += ((size_t)N * 4 + 255) & ~(size_t)255;
    int*   cnt       = (int*)w;    w += ((size_t)N * 4 + 255) & ~(size_t)255;
    int*   excl_tmp  = (int*)w;    w += ((size_t)N * 4 + 255) & ~(size_t)255;
    int*   blksum    = (int*)w;    w += 256 * 4;
    int*   row_start = (int*)w;    w += ((size_t)(N + 1) * 4 + 255) & ~(size_t)255;
    int*   cursor    = (int*)w;    w += ((size_t)N * 4 + 255) & ~(size_t)255;
    int*   csr_src   = (int*)w;    w += ((size_t)E * 4 + 255) & ~(size_t)255;
    unsigned char*  xq   = (unsigned char*)w;   w += ((size_t)N * INDIM + 255) & ~(size_t)255;   // fp8
    unsigned char*  Hq   = (unsigned char*)w;   w += ((size_t)N * HID + 255) & ~(size_t)255;     // fp8
    unsigned short* w1t  = (unsigned short*)w;  w += ((size_t)INDIM * HID * 2 + 255) & ~(size_t)255;
    unsigned short* w2t  = (unsigned short*)w;  w += ((size_t)HID * HID * 2 + 255) & ~(size_t)255;
    unsigned short* bufA = (unsigned short*)w;  w += (size_t)N * INDIM * 2;  // agg1 out (bf16, [N][128])
    unsigned short* bufB = (unsigned short*)w;  w += (size_t)N * HID * 2;    // h1 / h2 (bf16, [N][256])
    float* gbuf      = (float*)w;  w += (size_t)G * HID * 4;

    const int* src = ei;
    const int* dst = ei + E;

    // ---- weight transposes ----
    k_wt<INDIM><<<HID, INDIM, 0, stream>>>(W1, w1t);
    k_wt<HID><<<HID, HID, 0, stream>>>(W2, w2t);

    // ---- CSR build + dinv ----
    hipMemsetAsync(cnt, 0, (size_t)N * 4, stream);
    k_count<<<(E + 255) / 256, 256, 0, stream>>>(dst, E, cnt);
    k_scan_block<<<NB, 256, 0, stream>>>(cnt, excl_tmp, blksum, N);
    k_scan_top<<<1, 256, 0, stream>>>(blksum, NB);
    k_finalize_rows<<<NB, 256, 0, stream>>>(excl_tmp, blksum, cnt, row_start, cursor, dinv, N, E);
    k_fill<<<(E + 255) / 256, 256, 0, stream>>>(src, dst, E, cursor, csr_src);

    // ---- scaled fp8 cast: xq = fp8(x * dinv[row]) ----
    int nw = N * INDIM / 4;
    k_cast_q<<<(nw + 255) / 256, 256, 0, stream>>>(x, dinv, (unsigned int*)xq, nw);

    const int gemm_blocks = (N + 63) / 64;
    const int agg_blocks  = (N + 3) / 4;

    // ---- layer 1: aggregate (fp8 gather) in 128-dim, then GEMM(+bias+relu) ----
    k_agg_q<INDIM, false><<<agg_blocks, 256, 0, stream>>>(xq, dinv, row_start, csr_src, nullptr, bufA, N);
    k_gemm_mfma<INDIM, 1><<<gemm_blocks, 256, 0, stream>>>(bufA, w1t, b1, bufB, N);

    // ---- layer 2: GEMM(*dinv -> fp8), then aggregate(+bias+relu) in 256-dim ----
    k_gemm_mfma<HID, 2><<<gemm_blocks, 256, 0, stream>>>(bufB, w2t, dinv, Hq, N);
    k_agg_q<HID, true><<<agg_blocks, 256, 0, stream>>>(Hq, dinv, row_start, csr_src, b2, bufB, N);

    // ---- pool + classifier ----
    k_pool<<<G, 256, 0, stream>>>(bufB, batch, N, gbuf);
    k_cls<<<G, 128, 0, stream>>>(gbuf, W3, b3, W4, b4, (float*)d_out);
}